// Round 7
// 220.599 us; speedup vs baseline: 1.0002x; 1.0002x over previous
//
#include <hip/hip_runtime.h>
#include <hip/hip_bf16.h>

#define TTT_LR 0.01f
#define LN_EPS 1e-5f

// Problem dims (fixed by reference)
#define BB 4
#define SS 2048
#define DD 1024
#define DSZ 64
#define CHUNK 64
#define NC (SS / CHUNK)   // 32
#define NCAT 1152         // 64 k + 64 q + 1024 v output cols
#define NCVT (NCAT * DD / 4 / 256)   // 1152 cvt blocks
#define MiB (1024ull * 1024ull)

typedef __hip_bfloat16 bf16;
typedef __bf16 bf16x8 __attribute__((ext_vector_type(8)));
typedef float f32x4 __attribute__((ext_vector_type(4)));

__device__ __forceinline__ void gload_lds16(const void* g, void* l) {
    __builtin_amdgcn_global_load_lds(
        (const __attribute__((address_space(1))) unsigned int*)g,
        (__attribute__((address_space(3))) unsigned int*)l, 16, 0, 0);
}

// ---------------------------------------------------------------------------
// Kernel 1: merged pre-pass. Blocks [0,NCVT): Wk/Wq/Wv -> bf16 Wcat.
// Blocks [NCVT, NCVT+B*S): LayerNorm row -> h (bf16).
// ---------------------------------------------------------------------------
__global__ __launch_bounds__(256) void pre_kernel(
    const float* __restrict__ Wk, const float* __restrict__ Wq,
    const float* __restrict__ Wv, bf16* __restrict__ Wcat,
    const float* __restrict__ x, const float* __restrict__ gamma,
    const float* __restrict__ beta, bf16* __restrict__ hb)
{
    __shared__ float wsum[4], wsum2[4];
    const int tid = threadIdx.x;

    if (blockIdx.x < NCVT) {
        const int i = blockIdx.x * 256 + tid;           // float4 group index
        const int idx = i * 4;
        const int row = idx >> 10, col = idx & 1023;
        const float* src = (row < 64)  ? (Wk + (size_t)row * DD)
                         : (row < 128) ? (Wq + (size_t)(row - 64) * DD)
                                       : (Wv + (size_t)(row - 128) * DD);
        float4 v = *reinterpret_cast<const float4*>(src + col);
        bf16 h4[4] = {__float2bfloat16(v.x), __float2bfloat16(v.y),
                      __float2bfloat16(v.z), __float2bfloat16(v.w)};
        *reinterpret_cast<ushort4*>(Wcat + idx) = *reinterpret_cast<ushort4*>(h4);
        return;
    }

    const int row = blockIdx.x - NCVT;
    const int lane = tid & 63, wave = tid >> 6;

    float4 v0 = *reinterpret_cast<const float4*>(x + (size_t)row * DD + tid * 4);
    float s = v0.x + v0.y + v0.z + v0.w;
    float s2 = fmaf(v0.x, v0.x, fmaf(v0.y, v0.y, fmaf(v0.z, v0.z, v0.w * v0.w)));
    #pragma unroll
    for (int off = 32; off > 0; off >>= 1) {
        s  += __shfl_down(s, off, 64);
        s2 += __shfl_down(s2, off, 64);
    }
    if (lane == 0) { wsum[wave] = s; wsum2[wave] = s2; }
    __syncthreads();
    s  = wsum[0] + wsum[1] + wsum[2] + wsum[3];
    s2 = wsum2[0] + wsum2[1] + wsum2[2] + wsum2[3];
    const float mu = s * (1.0f / DD);
    const float rs = rsqrtf(s2 * (1.0f / DD) - mu * mu + LN_EPS);

    float4 g  = *reinterpret_cast<const float4*>(gamma + tid * 4);
    float4 be = *reinterpret_cast<const float4*>(beta + tid * 4);
    bf16 h4[4];
    h4[0] = __float2bfloat16((v0.x - mu) * rs * g.x + be.x);
    h4[1] = __float2bfloat16((v0.y - mu) * rs * g.y + be.y);
    h4[2] = __float2bfloat16((v0.z - mu) * rs * g.z + be.z);
    h4[3] = __float2bfloat16((v0.w - mu) * rs * g.w + be.w);
    *reinterpret_cast<ushort4*>(hb + (size_t)row * DD + tid * 4) =
        *reinterpret_cast<ushort4*>(h4);
}

// ---------------------------------------------------------------------------
// Kernel 2: fused kqv = h @ Wcat^T + bias. 128x128 tile, BK=64,
// global_load_lds(16B) staging, XOR-swizzled 16B blocks. k/q stored fp32;
// v stored bf16 (vbuf16) for the MFMA scan.
// Grid: 1-D 576 blocks with chunked XCD swizzle (576 % 8 == 0 -> bijective).
// Tile order n-fastest, so each XCD owns 8 full M-panels x all 9 N-tiles:
// per-XCD L2 working set = 8*256KB h-panels + 2.4MB Wcat (both L2-resident).
// ---------------------------------------------------------------------------
__global__ __launch_bounds__(256) void kqv_kernel(
    const bf16* __restrict__ h, const bf16* __restrict__ Wcat,
    const float* __restrict__ bk, const float* __restrict__ bq,
    const float* __restrict__ bv,
    float* __restrict__ kbuf, float* __restrict__ qbuf, bf16* __restrict__ vbuf16)
{
    __shared__ bf16 Ash[128 * 64];
    __shared__ bf16 Bsh[128 * 64];
    const int tid = threadIdx.x, lane = tid & 63, wave = tid >> 6;
    const int m = lane & 15, quad = lane >> 4;
    const int wr = wave >> 1, wc = wave & 1;

    // chunked XCD swizzle: hw assigns block id -> XCD (id % 8); we want
    // logical tile t on XCD t/72, so t = (id%8)*72 + id/8.
    const int id = blockIdx.x;
    const int tile = (id & 7) * 72 + (id >> 3);
    const int mtile = tile / 9;          // 0..63 M-panel
    const int ntile = tile % 9;          // 0..8  N-panel (n-fastest in-XCD)
    const int m0 = mtile * 128;          // h rows
    const int n0 = ntile * 128;          // Wcat rows

    const int srow = wave * 8 + (lane >> 3);   // staging row (+ i*32)
    const int scb = lane & 7;                  // staging 16B-block in row

    f32x4 acc[4][4] = {};

    for (int k0 = 0; k0 < DD; k0 += 64) {
        __syncthreads();                       // prior frag reads done
        #pragma unroll
        for (int i = 0; i < 4; ++i) {
            const int row = i * 32 + srow;
            const int g16 = scb ^ (row & 7);   // swizzled source block
            gload_lds16(h    + (size_t)(m0 + row) * DD + k0 + g16 * 8,
                        (char*)Ash + (size_t)(i * 32 + wave * 8) * 128);
            gload_lds16(Wcat + (size_t)(n0 + row) * DD + k0 + g16 * 8,
                        (char*)Bsh + (size_t)(i * 32 + wave * 8) * 128);
        }
        __syncthreads();                       // DMA drained (vmcnt0 @ barrier)
        #pragma unroll
        for (int ks = 0; ks < 2; ++ks) {
            bf16x8 af[4], bfr[4];
            #pragma unroll
            for (int mt = 0; mt < 4; ++mt) {
                const int row = wr * 64 + mt * 16 + m;
                const int kb = (ks * 4 + quad) ^ (row & 7);
                af[mt] = *reinterpret_cast<const bf16x8*>(&Ash[row * 64 + kb * 8]);
            }
            #pragma unroll
            for (int nt = 0; nt < 4; ++nt) {
                const int row = wc * 64 + nt * 16 + m;
                const int kb = (ks * 4 + quad) ^ (row & 7);
                bfr[nt] = *reinterpret_cast<const bf16x8*>(&Bsh[row * 64 + kb * 8]);
            }
            #pragma unroll
            for (int mt = 0; mt < 4; ++mt)
                #pragma unroll
                for (int nt = 0; nt < 4; ++nt)
                    acc[mt][nt] = __builtin_amdgcn_mfma_f32_16x16x32_bf16(
                        af[mt], bfr[nt], acc[mt][nt], 0, 0, 0);
        }
    }

    #pragma unroll
    for (int nt = 0; nt < 4; ++nt) {
        const int n = n0 + wc * 64 + nt * 16 + m;
        if (n < 64) {
            const float bias = bk[n];
            #pragma unroll
            for (int mt = 0; mt < 4; ++mt) {
                const int row = m0 + wr * 64 + mt * 16 + quad * 4;
                #pragma unroll
                for (int r = 0; r < 4; ++r)
                    kbuf[(size_t)(row + r) * DSZ + n] = acc[mt][nt][r] + bias;
            }
        } else if (n < 128) {
            const float bias = bq[n - 64];
            #pragma unroll
            for (int mt = 0; mt < 4; ++mt) {
                const int row = m0 + wr * 64 + mt * 16 + quad * 4;
                #pragma unroll
                for (int r = 0; r < 4; ++r)
                    qbuf[(size_t)(row + r) * DSZ + (n - 64)] = acc[mt][nt][r] + bias;
            }
        } else {
            const float bias = bv[n - 128];
            #pragma unroll
            for (int mt = 0; mt < 4; ++mt) {
                const int row = m0 + wr * 64 + mt * 16 + quad * 4;
                #pragma unroll
                for (int r = 0; r < 4; ++r)
                    vbuf16[(size_t)(row + r) * DD + (n - 128)] =
                        __float2bfloat16(acc[mt][nt][r] + bias);
            }
        }
    }
}

// ---------------------------------------------------------------------------
// Kernel 3: per-(b,chunk) prep — MFMA. Outputs 4 chunk matrices (bf16):
//   Qtb16 = Q - Astl*B          (A-rows = t)
//   AMb16 = Astl*(lr*Minv)      (A-rows = t)
//   Tb16  = -K^T B              (A-rows = s)   [Z-update transition]
//   Wb16  = K^T (lr*Minv)       (A-rows = s)   [Z-update drive]
// where B = (lr*Minv)*K, Minv = (I + lr*trilS(G))^-1 (serial solve, fp32),
// G = K K^T, A = Q K^T (strict-lower).
// ---------------------------------------------------------------------------
__global__ __launch_bounds__(256) void prep_kernel(
    const float* __restrict__ kbuf, const float* __restrict__ qbuf,
    bf16* __restrict__ Tb16, bf16* __restrict__ Wb16,
    bf16* __restrict__ AMb16, bf16* __restrict__ Qtb16)
{
    __shared__ bf16 K16[64 * 72];      // K  [t][s]
    __shared__ bf16 Kt16[64 * 72];     // K^T [s][t]
    __shared__ bf16 Q16[64 * 72];      // Q  [t][s]
    __shared__ bf16 Astl[64 * 72];     // strict-lower A, zeros elsewhere
    __shared__ bf16 Minv16[64 * 72];   // lr*Minv [t][j]
    __shared__ bf16 MinvT16[64 * 72];  // (lr*Minv)^T [j][t]
    __shared__ bf16 BnegT[64 * 72];    // -B^T [s][t]
    __shared__ float Gf[64 * 65];      // lr*G (fp32, solve input)
    __shared__ float Mf[64 * 65];      // Minv (fp32, solve output)

    const int c = blockIdx.x, b = blockIdx.y;
    const int tid = threadIdx.x, lane = tid & 63, w = tid >> 6;
    const int m = lane & 15, quad = lane >> 4;
    const float* kp = kbuf + ((size_t)b * SS + c * 64) * DSZ;
    const float* qp = qbuf + ((size_t)b * SS + c * 64) * DSZ;
    const size_t cb = ((size_t)b * NC + c) * 4096;

    // ---- stage K (row + transposed) and Q as bf16
    #pragma unroll
    for (int it = 0; it < 4; ++it) {
        const int f4 = tid + it * 256;          // float4 index 0..1023
        const int t = f4 >> 4;
        const int s = (f4 & 15) * 4;
        float4 kv = *reinterpret_cast<const float4*>(kp + t * DSZ + s);
        float4 qv = *reinterpret_cast<const float4*>(qp + t * DSZ + s);
        bf16 kb4[4] = {__float2bfloat16(kv.x), __float2bfloat16(kv.y),
                       __float2bfloat16(kv.z), __float2bfloat16(kv.w)};
        bf16 qb4[4] = {__float2bfloat16(qv.x), __float2bfloat16(qv.y),
                       __float2bfloat16(qv.z), __float2bfloat16(qv.w)};
        *reinterpret_cast<ushort4*>(&K16[t * 72 + s]) = *reinterpret_cast<ushort4*>(kb4);
        *reinterpret_cast<ushort4*>(&Q16[t * 72 + s]) = *reinterpret_cast<ushort4*>(qb4);
        #pragma unroll
        for (int i = 0; i < 4; ++i) Kt16[(s + i) * 72 + t] = kb4[i];
    }
    __syncthreads();

    // ---- G = K K^T (store lr*G fp32), A = Q K^T (store strict-lower bf16)
    bf16x8 afK[2], afQ[2], bfK[4][2];
    #pragma unroll
    for (int ks = 0; ks < 2; ++ks) {
        afK[ks] = *reinterpret_cast<const bf16x8*>(&K16[(w * 16 + m) * 72 + ks * 32 + quad * 8]);
        afQ[ks] = *reinterpret_cast<const bf16x8*>(&Q16[(w * 16 + m) * 72 + ks * 32 + quad * 8]);
        #pragma unroll
        for (int nt = 0; nt < 4; ++nt)
            bfK[nt][ks] = *reinterpret_cast<const bf16x8*>(&K16[(nt * 16 + m) * 72 + ks * 32 + quad * 8]);
    }
    f32x4 gacc[4] = {}, aacc[4] = {};
    #pragma unroll
    for (int ks = 0; ks < 2; ++ks)
        #pragma unroll
        for (int nt = 0; nt < 4; ++nt) {
            gacc[nt] = __builtin_amdgcn_mfma_f32_16x16x32_bf16(afK[ks], bfK[nt][ks], gacc[nt], 0, 0, 0);
            aacc[nt] = __builtin_amdgcn_mfma_f32_16x16x32_bf16(afQ[ks], bfK[nt][ks], aacc[nt], 0, 0, 0);
        }
    #pragma unroll
    for (int nt = 0; nt < 4; ++nt)
        #pragma unroll
        for (int r = 0; r < 4; ++r) {
            const int t = w * 16 + quad * 4 + r, j = nt * 16 + m;
            Gf[t * 65 + j] = TTT_LR * gacc[nt][r];
            Astl[t * 72 + j] = __float2bfloat16(j < t ? aacc[nt][r] : 0.f);
        }
    __syncthreads();

    // ---- serial forward-substitution: Minv = (I + lr*trilS(G))^-1 (fp32)
    if (tid < 64) {
        for (int t = 0; t < 64; ++t) {
            float acc = (t == tid) ? 1.f : 0.f;
            for (int i = 0; i < t; ++i)
                acc = fmaf(-Gf[t * 65 + i], Mf[i * 65 + tid], acc);
            Mf[t * 65 + tid] = acc;
        }
    }
    __syncthreads();

    // ---- lr*Minv -> bf16 (row + transposed)
    #pragma unroll
    for (int it = 0; it < 16; ++it) {
        const int e = tid + it * 256;           // 0..4095
        const int t = e >> 6, j = e & 63;
        const bf16 vb = __float2bfloat16(TTT_LR * Mf[t * 65 + j]);
        Minv16[t * 72 + j] = vb;
        MinvT16[j * 72 + t] = vb;
    }
    __syncthreads();

    // ---- B = (lr*Minv) * K  via mfma(Minv16 rows, Kt16 rows)
    bf16x8 afM[2], afA[2], afKt[2], bfKt[4][2], bfMt[4][2];
    #pragma unroll
    for (int ks = 0; ks < 2; ++ks) {
        afM[ks]  = *reinterpret_cast<const bf16x8*>(&Minv16[(w * 16 + m) * 72 + ks * 32 + quad * 8]);
        afA[ks]  = *reinterpret_cast<const bf16x8*>(&Astl[(w * 16 + m) * 72 + ks * 32 + quad * 8]);
        afKt[ks] = *reinterpret_cast<const bf16x8*>(&Kt16[(w * 16 + m) * 72 + ks * 32 + quad * 8]);
        #pragma unroll
        for (int nt = 0; nt < 4; ++nt) {
            bfKt[nt][ks] = *reinterpret_cast<const bf16x8*>(&Kt16[(nt * 16 + m) * 72 + ks * 32 + quad * 8]);
            bfMt[nt][ks] = *reinterpret_cast<const bf16x8*>(&MinvT16[(nt * 16 + m) * 72 + ks * 32 + quad * 8]);
        }
    }
    f32x4 bacc[4] = {};
    #pragma unroll
    for (int ks = 0; ks < 2; ++ks)
        #pragma unroll
        for (int nt = 0; nt < 4; ++nt)
            bacc[nt] = __builtin_amdgcn_mfma_f32_16x16x32_bf16(afM[ks], bfKt[nt][ks], bacc[nt], 0, 0, 0);
    #pragma unroll
    for (int nt = 0; nt < 4; ++nt)
        #pragma unroll
        for (int r = 0; r < 4; ++r) {
            const int t = w * 16 + quad * 4 + r, s = nt * 16 + m;
            BnegT[s * 72 + t] = __float2bfloat16(-bacc[nt][r]);
        }
    __syncthreads();

    // ---- Qt = Q - Astl*B (C-init = Q), AM = Astl*(lr*Minv),
    //      T' = -K^T B = mfma(Kt rows, BnegT rows),
    //      W  =  K^T (lr*Minv) = mfma(Kt rows, MinvT rows)
    f32x4 qtacc[4], amacc[4] = {}, tacc[4] = {}, wacc[4] = {};
    #pragma unroll
    for (int nt = 0; nt < 4; ++nt)
        #pragma unroll
        for (int r = 0; r < 4; ++r)
            qtacc[nt][r] = qp[(w * 16 + quad * 4 + r) * DSZ + nt * 16 + m];
    #pragma unroll
    for (int ks = 0; ks < 2; ++ks)
        #pragma unroll
        for (int nt = 0; nt < 4; ++nt) {
            const bf16x8 bfBn = *reinterpret_cast<const bf16x8*>(
                &BnegT[(nt * 16 + m) * 72 + ks * 32 + quad * 8]);
            qtacc[nt] = __builtin_amdgcn_mfma_f32_16x16x32_bf16(afA[ks], bfBn, qtacc[nt], 0, 0, 0);
            amacc[nt] = __builtin_amdgcn_mfma_f32_16x16x32_bf16(afA[ks], bfMt[nt][ks], amacc[nt], 0, 0, 0);
            tacc[nt]  = __builtin_amdgcn_mfma_f32_16x16x32_bf16(afKt[ks], bfBn, tacc[nt], 0, 0, 0);
            wacc[nt]  = __builtin_amdgcn_mfma_f32_16x16x32_bf16(afKt[ks], bfMt[nt][ks], wacc[nt], 0, 0, 0);
        }
    #pragma unroll
    for (int nt = 0; nt < 4; ++nt)
        #pragma unroll
        for (int r = 0; r < 4; ++r) {
            const int row = w * 16 + quad * 4 + r, col = nt * 16 + m;
            Qtb16[cb + row * 64 + col] = __float2bfloat16(qtacc[nt][r]);
            AMb16[cb + row * 64 + col] = __float2bfloat16(amacc[nt][r]);
            Tb16[cb + row * 64 + col]  = __float2bfloat16(tacc[nt][r]);
            Wb16[cb + row * 64 + col]  = __float2bfloat16(wacc[nt][r]);
        }
}

// ---------------------------------------------------------------------------
// Kernel 4: fused scan, ONE barrier per chunk. 256 blocks (64 d-stripes x
// 4 batches), 4 waves. Per chunk (8 MFMAs):
//   out  = x + AM V + Qt Z                         (single store)
//   zacc += T' Z + W V    (persistent fp32; Z_bf16 double-buffered in LDS)
// Z/V both read as B-frags from [d][.] LDS layouts; prefetch c+1 globals.
// Grid: 1-D 256 blocks with chunked XCD swizzle (b-major, dblk-fastest):
// 32 consecutive d-stripes of one b per XCD -> v16/x cache-line sharing is
// intra-XCD; T/W/AM/Qt chunk matrices fetched 2x (was 8x).
// ---------------------------------------------------------------------------
struct ChunkRegs {
    bf16x8 T0, T1, W0, W1, A0, A1, Q0, Q1;
    alignas(8) unsigned short va[4], vb[4];   // V rows (vj2, vj2+1) x 4 cols
    float xld[4];
};

__global__ __launch_bounds__(256) void scan2_kernel(
    const bf16* __restrict__ Tb16, const bf16* __restrict__ Wb16,
    const bf16* __restrict__ AMb16, const bf16* __restrict__ Qtb16,
    const bf16* __restrict__ v16, const float* __restrict__ x,
    float* __restrict__ out)
{
    __shared__ bf16 Zsh[2][16][72];
    __shared__ bf16 Vsh[2][16][72];
    // chunked XCD swizzle (256 % 8 == 0 -> bijective): tile = b*64 + dblk
    const int id = blockIdx.x;
    const int tile = (id & 7) * 32 + (id >> 3);
    const int b = tile >> 6, dblk = tile & 63;
    const int tid = threadIdx.x, lane = tid & 63, w = tid >> 6;
    const int m = lane & 15, quad = lane >> 4;
    const int d0 = dblk * 16;
    const int arow = w * 16 + m;          // A-frag row (all matmuls)
    const int trow = w * 16 + quad * 4;   // first C/D row for this thread

    // V staging: tid<128; row pair vj2, col group vd (4 cols)
    const bool vact = tid < 128;
    const int vj2 = (tid & 31) * 2;
    const int vd = (tid >> 5) * 4;        // 0,4,8,12 for tid<128

    f32x4 zacc = {0.f, 0.f, 0.f, 0.f};
    for (int i = tid; i < 16 * 72; i += 256)
        (&Zsh[0][0][0])[i] = __float2bfloat16(0.f);

    auto load_chunk = [&](int c, ChunkRegs& R) {
        const size_t cb = ((size_t)b * NC + c) * 4096;
        const size_t rowbase = (size_t)b * SS + (size_t)c * 64;
        R.T0 = *reinterpret_cast<const bf16x8*>(Tb16 + cb + arow * 64 + quad * 8);
        R.T1 = *reinterpret_cast<const bf16x8*>(Tb16 + cb + arow * 64 + 32 + quad * 8);
        R.W0 = *reinterpret_cast<const bf16x8*>(Wb16 + cb + arow * 64 + quad * 8);
        R.W1 = *reinterpret_cast<const bf16x8*>(Wb16 + cb + arow * 64 + 32 + quad * 8);
        R.A0 = *reinterpret_cast<const bf16x8*>(AMb16 + cb + arow * 64 + quad * 8);
        R.A1 = *reinterpret_cast<const bf16x8*>(AMb16 + cb + arow * 64 + 32 + quad * 8);
        R.Q0 = *reinterpret_cast<const bf16x8*>(Qtb16 + cb + arow * 64 + quad * 8);
        R.Q1 = *reinterpret_cast<const bf16x8*>(Qtb16 + cb + arow * 64 + 32 + quad * 8);
        if (vact) {
            *reinterpret_cast<uint2*>(R.va) = *reinterpret_cast<const uint2*>(
                v16 + (rowbase + vj2) * DD + d0 + vd);
            *reinterpret_cast<uint2*>(R.vb) = *reinterpret_cast<const uint2*>(
                v16 + (rowbase + vj2 + 1) * DD + d0 + vd);
        }
        const size_t gbase = (rowbase + trow) * DD + d0 + m;
        #pragma unroll
        for (int r = 0; r < 4; ++r) R.xld[r] = x[gbase + (size_t)r * DD];
    };

    auto stage_v = [&](const ChunkRegs& R, int buf) {
        if (vact) {
            #pragma unroll
            for (int i = 0; i < 4; ++i) {
                const unsigned int pack =
                    (unsigned int)R.va[i] | ((unsigned int)R.vb[i] << 16);
                *reinterpret_cast<unsigned int*>(&Vsh[buf][vd + i][vj2]) = pack;
            }
        }
    };

    auto compute = [&](const ChunkRegs& R, int c, int buf) {
        const size_t gbase = ((size_t)b * SS + (size_t)c * 64 + trow) * DD + d0 + m;
        const bf16x8 z0 = *reinterpret_cast<const bf16x8*>(&Zsh[buf][m][quad * 8]);
        const bf16x8 z1 = *reinterpret_cast<const bf16x8*>(&Zsh[buf][m][32 + quad * 8]);
        const bf16x8 v0 = *reinterpret_cast<const bf16x8*>(&Vsh[buf][m][quad * 8]);
        const bf16x8 v1 = *reinterpret_cast<const bf16x8*>(&Vsh[buf][m][32 + quad * 8]);

        // Z update (persistent fp32 accumulator, increment form)
        zacc = __builtin_amdgcn_mfma_f32_16x16x32_bf16(R.T0, z0, zacc, 0, 0, 0);
        zacc = __builtin_amdgcn_mfma_f32_16x16x32_bf16(R.T1, z1, zacc, 0, 0, 0);
        zacc = __builtin_amdgcn_mfma_f32_16x16x32_bf16(R.W0, v0, zacc, 0, 0, 0);
        zacc = __builtin_amdgcn_mfma_f32_16x16x32_bf16(R.W1, v1, zacc, 0, 0, 0);

        // y = Qt Z + AM V
        f32x4 y = {0.f, 0.f, 0.f, 0.f};
        y = __builtin_amdgcn_mfma_f32_16x16x32_bf16(R.Q0, z0, y, 0, 0, 0);
        y = __builtin_amdgcn_mfma_f32_16x16x32_bf16(R.Q1, z1, y, 0, 0, 0);
        y = __builtin_amdgcn_mfma_f32_16x16x32_bf16(R.A0, v0, y, 0, 0, 0);
        y = __builtin_amdgcn_mfma_f32_16x16x32_bf16(R.A1, v1, y, 0, 0, 0);

        // write new Z (bf16) into the other buffer
        alignas(8) bf16 zb[4];
        #pragma unroll
        for (int r = 0; r < 4; ++r) zb[r] = __float2bfloat16(zacc[r]);
        *reinterpret_cast<uint2*>(&Zsh[buf ^ 1][m][trow]) =
            *reinterpret_cast<uint2*>(zb);

        #pragma unroll
        for (int r = 0; r < 4; ++r)
            out[gbase + (size_t)r * DD] = R.xld[r] + y[r];
    };

    ChunkRegs R0, R1;
    load_chunk(0, R0);
    for (int c = 0; c < NC; c += 2) {
        // phase 0: chunk c (buffers 0), prefetch c+1
        stage_v(R0, 0);
        __syncthreads();                  // Vsh[0] + Zsh[0] ready
        load_chunk(c + 1, R1);
        compute(R0, c, 0);                // reads buf 0, writes Zsh[1]
        // phase 1: chunk c+1 (buffers 1), prefetch c+2
        stage_v(R1, 1);
        __syncthreads();                  // Vsh[1] + Zsh[1] ready
        if (c + 2 < NC) load_chunk(c + 2, R0);
        compute(R1, c + 1, 1);            // reads buf 1, writes Zsh[0]
    }
}

// ---------------------------------------------------------------------------
extern "C" void kernel_launch(void* const* d_in, const int* in_sizes, int n_in,
                              void* d_out, int out_size, void* d_ws, size_t ws_size,
                              hipStream_t stream)
{
    const float* x     = (const float*)d_in[0];
    const float* Wk    = (const float*)d_in[1];
    const float* bk    = (const float*)d_in[2];
    const float* Wv    = (const float*)d_in[3];
    const float* bv    = (const float*)d_in[4];
    const float* Wq    = (const float*)d_in[5];
    const float* bq    = (const float*)d_in[6];
    const float* gamma = (const float*)d_in[7];
    const float* beta  = (const float*)d_in[8];

    char* ws = (char*)d_ws;
    // layout (~38.25 MiB):
    //   [0,16 MiB): hb (bf16, pre->kqv) -- dead after kqv; reused by prep as:
    //     Tb16@0, Qtb16@1MiB, Wb16@2MiB, AMb16@3MiB (1 MiB each)
    //   [16 MiB, +2.25): Wcat (bf16 1152x1024)
    //   +2 MiB: kbuf (fp32)   +2 MiB: qbuf (fp32)
    //   +16 MiB: vbuf16 (bf16 8192x1024)
    const size_t WCAT_B = (size_t)NCAT * DD * 2;   // 2.25 MiB
    bf16*  hb    = (bf16*)ws;
    bf16*  Tb16  = (bf16*)(ws + 0 * MiB);
    bf16*  Qtb16 = (bf16*)(ws + 1 * MiB);
    bf16*  Wb16  = (bf16*)(ws + 2 * MiB);
    bf16*  AMb16 = (bf16*)(ws + 3 * MiB);
    bf16*  Wcat  = (bf16*)(ws + 16 * MiB);
    float* kbuf  = (float*)(ws + 16 * MiB + WCAT_B);
    float* qbuf  = (float*)(ws + 18 * MiB + WCAT_B);
    bf16*  v16   = (bf16*)(ws + 20 * MiB + WCAT_B);

    pre_kernel<<<NCVT + BB * SS, 256, 0, stream>>>(
        Wk, Wq, Wv, Wcat, x, gamma, beta, hb);
    kqv_kernel<<<dim3(576), 256, 0, stream>>>(
        hb, Wcat, bk, bq, bv, kbuf, qbuf, v16);
    prep_kernel<<<dim3(NC, BB), 256, 0, stream>>>(
        kbuf, qbuf, Tb16, Wb16, AMb16, Qtb16);
    scan2_kernel<<<dim3(256), 256, 0, stream>>>(
        Tb16, Wb16, AMb16, Qtb16, v16, x, (float*)d_out);
}

// Round 11
// 208.188 us; speedup vs baseline: 1.0598x; 1.0596x over previous
//
#include <hip/hip_runtime.h>
#include <hip/hip_bf16.h>

#define TTT_LR 0.01f
#define LN_EPS 1e-5f

// Problem dims (fixed by reference)
#define BB 4
#define SS 2048
#define DD 1024
#define DSZ 64
#define CHUNK 64
#define NC (SS / CHUNK)   // 32
#define NCAT 1152         // 64 k + 64 q + 1024 v output cols
#define NCVT (NCAT * DD / 4 / 256)   // 1152 cvt blocks
#define MiB (1024ull * 1024ull)

typedef __hip_bfloat16 bf16;
typedef __bf16 bf16x8 __attribute__((ext_vector_type(8)));
typedef float f32x4 __attribute__((ext_vector_type(4)));

__device__ __forceinline__ void gload_lds16(const void* g, void* l) {
    __builtin_amdgcn_global_load_lds(
        (const __attribute__((address_space(1))) unsigned int*)g,
        (__attribute__((address_space(3))) unsigned int*)l, 16, 0, 0);
}

// ---------------------------------------------------------------------------
// Kernel 1: merged pre-pass. Blocks [0,NCVT): Wk/Wq/Wv -> bf16 Wcat.
// Blocks [NCVT, NCVT+B*S): LayerNorm row -> h (bf16).
// ---------------------------------------------------------------------------
__global__ __launch_bounds__(256) void pre_kernel(
    const float* __restrict__ Wk, const float* __restrict__ Wq,
    const float* __restrict__ Wv, bf16* __restrict__ Wcat,
    const float* __restrict__ x, const float* __restrict__ gamma,
    const float* __restrict__ beta, bf16* __restrict__ hb)
{
    __shared__ float wsum[4], wsum2[4];
    const int tid = threadIdx.x;

    if (blockIdx.x < NCVT) {
        const int i = blockIdx.x * 256 + tid;           // float4 group index
        const int idx = i * 4;
        const int row = idx >> 10, col = idx & 1023;
        const float* src = (row < 64)  ? (Wk + (size_t)row * DD)
                         : (row < 128) ? (Wq + (size_t)(row - 64) * DD)
                                       : (Wv + (size_t)(row - 128) * DD);
        float4 v = *reinterpret_cast<const float4*>(src + col);
        bf16 h4[4] = {__float2bfloat16(v.x), __float2bfloat16(v.y),
                      __float2bfloat16(v.z), __float2bfloat16(v.w)};
        *reinterpret_cast<ushort4*>(Wcat + idx) = *reinterpret_cast<ushort4*>(h4);
        return;
    }

    const int row = blockIdx.x - NCVT;
    const int lane = tid & 63, wave = tid >> 6;

    float4 v0 = *reinterpret_cast<const float4*>(x + (size_t)row * DD + tid * 4);
    float s = v0.x + v0.y + v0.z + v0.w;
    float s2 = fmaf(v0.x, v0.x, fmaf(v0.y, v0.y, fmaf(v0.z, v0.z, v0.w * v0.w)));
    #pragma unroll
    for (int off = 32; off > 0; off >>= 1) {
        s  += __shfl_down(s, off, 64);
        s2 += __shfl_down(s2, off, 64);
    }
    if (lane == 0) { wsum[wave] = s; wsum2[wave] = s2; }
    __syncthreads();
    s  = wsum[0] + wsum[1] + wsum[2] + wsum[3];
    s2 = wsum2[0] + wsum2[1] + wsum2[2] + wsum2[3];
    const float mu = s * (1.0f / DD);
    const float rs = rsqrtf(s2 * (1.0f / DD) - mu * mu + LN_EPS);

    float4 g  = *reinterpret_cast<const float4*>(gamma + tid * 4);
    float4 be = *reinterpret_cast<const float4*>(beta + tid * 4);
    bf16 h4[4];
    h4[0] = __float2bfloat16((v0.x - mu) * rs * g.x + be.x);
    h4[1] = __float2bfloat16((v0.y - mu) * rs * g.y + be.y);
    h4[2] = __float2bfloat16((v0.z - mu) * rs * g.z + be.z);
    h4[3] = __float2bfloat16((v0.w - mu) * rs * g.w + be.w);
    *reinterpret_cast<ushort4*>(hb + (size_t)row * DD + tid * 4) =
        *reinterpret_cast<ushort4*>(h4);
}

// ---------------------------------------------------------------------------
// Kernel 2: fused kqv = h @ Wcat^T + bias. 64x128 tile (was 128x128), BK=64,
// global_load_lds(16B) staging, XOR-swizzled 16B blocks. k/q stored fp32;
// v stored bf16 (vbuf16) for the MFMA scan.
// Retile rationale (R7 counters): FETCH fixed (83->27MB) but dur flat ->
// latency-bound at 2.25 blocks/CU (9 waves/CU). 64-row M-tile doubles the
// grid to 1152 = 4.5 blocks/CU (18 waves/CU), halves acc VGPR (64->32) and
// LDS (32->24KB), tail util 90%.
// Grid: 1-D 1152 blocks, chunked XCD swizzle (1152 = 8*144 -> bijective).
// n-fastest in-XCD: per-XCD L2 set = 16 A-panels (2MB) + Wcat (2.25MB).
// ---------------------------------------------------------------------------
__global__ __launch_bounds__(256) void kqv_kernel(
    const bf16* __restrict__ h, const bf16* __restrict__ Wcat,
    const float* __restrict__ bk, const float* __restrict__ bq,
    const float* __restrict__ bv,
    float* __restrict__ kbuf, float* __restrict__ qbuf, bf16* __restrict__ vbuf16)
{
    __shared__ bf16 Ash[64 * 64];
    __shared__ bf16 Bsh[128 * 64];
    const int tid = threadIdx.x, lane = tid & 63, wave = tid >> 6;
    const int m = lane & 15, quad = lane >> 4;
    const int wr = wave >> 1, wc = wave & 1;   // wave owns 32x64 of 64x128

    // chunked XCD swizzle: hw assigns block id -> XCD (id % 8); logical tile
    // t on XCD t/144, so t = (id%8)*144 + id/8.
    const int id = blockIdx.x;
    const int tile = (id & 7) * 144 + (id >> 3);
    const int mtile = tile / 9;          // 0..127 M-panel (64 rows)
    const int ntile = tile % 9;          // 0..8   N-panel (n-fastest in-XCD)
    const int m0 = mtile * 64;           // h rows
    const int n0 = ntile * 128;          // Wcat rows

    const int srow = wave * 8 + (lane >> 3);   // staging row (+ i*32)
    const int scb = lane & 7;                  // staging 16B-block in row

    f32x4 acc[2][4] = {};

    for (int k0 = 0; k0 < DD; k0 += 64) {
        __syncthreads();                       // prior frag reads done
        // A: 64 rows (2 calls), B: 128 rows (4 calls)
        #pragma unroll
        for (int i = 0; i < 2; ++i) {
            const int row = i * 32 + srow;
            const int g16 = scb ^ (row & 7);   // swizzled source block
            gload_lds16(h    + (size_t)(m0 + row) * DD + k0 + g16 * 8,
                        (char*)Ash + (size_t)(i * 32 + wave * 8) * 128);
        }
        #pragma unroll
        for (int i = 0; i < 4; ++i) {
            const int row = i * 32 + srow;
            const int g16 = scb ^ (row & 7);
            gload_lds16(Wcat + (size_t)(n0 + row) * DD + k0 + g16 * 8,
                        (char*)Bsh + (size_t)(i * 32 + wave * 8) * 128);
        }
        __syncthreads();                       // DMA drained (vmcnt0 @ barrier)
        #pragma unroll
        for (int ks = 0; ks < 2; ++ks) {
            bf16x8 af[2], bfr[4];
            #pragma unroll
            for (int mt = 0; mt < 2; ++mt) {
                const int row = wr * 32 + mt * 16 + m;
                const int kb = (ks * 4 + quad) ^ (row & 7);
                af[mt] = *reinterpret_cast<const bf16x8*>(&Ash[row * 64 + kb * 8]);
            }
            #pragma unroll
            for (int nt = 0; nt < 4; ++nt) {
                const int row = wc * 64 + nt * 16 + m;
                const int kb = (ks * 4 + quad) ^ (row & 7);
                bfr[nt] = *reinterpret_cast<const bf16x8*>(&Bsh[row * 64 + kb * 8]);
            }
            #pragma unroll
            for (int mt = 0; mt < 2; ++mt)
                #pragma unroll
                for (int nt = 0; nt < 4; ++nt)
                    acc[mt][nt] = __builtin_amdgcn_mfma_f32_16x16x32_bf16(
                        af[mt], bfr[nt], acc[mt][nt], 0, 0, 0);
        }
    }

    #pragma unroll
    for (int nt = 0; nt < 4; ++nt) {
        const int n = n0 + wc * 64 + nt * 16 + m;
        if (n < 64) {
            const float bias = bk[n];
            #pragma unroll
            for (int mt = 0; mt < 2; ++mt) {
                const int row = m0 + wr * 32 + mt * 16 + quad * 4;
                #pragma unroll
                for (int r = 0; r < 4; ++r)
                    kbuf[(size_t)(row + r) * DSZ + n] = acc[mt][nt][r] + bias;
            }
        } else if (n < 128) {
            const float bias = bq[n - 64];
            #pragma unroll
            for (int mt = 0; mt < 2; ++mt) {
                const int row = m0 + wr * 32 + mt * 16 + quad * 4;
                #pragma unroll
                for (int r = 0; r < 4; ++r)
                    qbuf[(size_t)(row + r) * DSZ + (n - 64)] = acc[mt][nt][r] + bias;
            }
        } else {
            const float bias = bv[n - 128];
            #pragma unroll
            for (int mt = 0; mt < 2; ++mt) {
                const int row = m0 + wr * 32 + mt * 16 + quad * 4;
                #pragma unroll
                for (int r = 0; r < 4; ++r)
                    vbuf16[(size_t)(row + r) * DD + (n - 128)] =
                        __float2bfloat16(acc[mt][nt][r] + bias);
            }
        }
    }
}

// ---------------------------------------------------------------------------
// Kernel 3: per-(b,chunk) prep — MFMA. Outputs 4 chunk matrices (bf16):
//   Qtb16 = Q - Astl*B          (A-rows = t)
//   AMb16 = Astl*(lr*Minv)      (A-rows = t)
//   Tb16  = -K^T B              (A-rows = s)   [Z-update transition]
//   Wb16  = K^T (lr*Minv)       (A-rows = s)   [Z-update drive]
// where B = (lr*Minv)*K, Minv = (I + lr*trilS(G))^-1 (serial solve, fp32),
// G = K K^T, A = Q K^T (strict-lower).
// ---------------------------------------------------------------------------
__global__ __launch_bounds__(256) void prep_kernel(
    const float* __restrict__ kbuf, const float* __restrict__ qbuf,
    bf16* __restrict__ Tb16, bf16* __restrict__ Wb16,
    bf16* __restrict__ AMb16, bf16* __restrict__ Qtb16)
{
    __shared__ bf16 K16[64 * 72];      // K  [t][s]
    __shared__ bf16 Kt16[64 * 72];     // K^T [s][t]
    __shared__ bf16 Q16[64 * 72];      // Q  [t][s]
    __shared__ bf16 Astl[64 * 72];     // strict-lower A, zeros elsewhere
    __shared__ bf16 Minv16[64 * 72];   // lr*Minv [t][j]
    __shared__ bf16 MinvT16[64 * 72];  // (lr*Minv)^T [j][t]
    __shared__ bf16 BnegT[64 * 72];    // -B^T [s][t]
    __shared__ float Gf[64 * 65];      // lr*G (fp32, solve input)
    __shared__ float Mf[64 * 65];      // Minv (fp32, solve output)

    const int c = blockIdx.x, b = blockIdx.y;
    const int tid = threadIdx.x, lane = tid & 63, w = tid >> 6;
    const int m = lane & 15, quad = lane >> 4;
    const float* kp = kbuf + ((size_t)b * SS + c * 64) * DSZ;
    const float* qp = qbuf + ((size_t)b * SS + c * 64) * DSZ;
    const size_t cb = ((size_t)b * NC + c) * 4096;

    // ---- stage K (row + transposed) and Q as bf16
    #pragma unroll
    for (int it = 0; it < 4; ++it) {
        const int f4 = tid + it * 256;          // float4 index 0..1023
        const int t = f4 >> 4;
        const int s = (f4 & 15) * 4;
        float4 kv = *reinterpret_cast<const float4*>(kp + t * DSZ + s);
        float4 qv = *reinterpret_cast<const float4*>(qp + t * DSZ + s);
        bf16 kb4[4] = {__float2bfloat16(kv.x), __float2bfloat16(kv.y),
                       __float2bfloat16(kv.z), __float2bfloat16(kv.w)};
        bf16 qb4[4] = {__float2bfloat16(qv.x), __float2bfloat16(qv.y),
                       __float2bfloat16(qv.z), __float2bfloat16(qv.w)};
        *reinterpret_cast<ushort4*>(&K16[t * 72 + s]) = *reinterpret_cast<ushort4*>(kb4);
        *reinterpret_cast<ushort4*>(&Q16[t * 72 + s]) = *reinterpret_cast<ushort4*>(qb4);
        #pragma unroll
        for (int i = 0; i < 4; ++i) Kt16[(s + i) * 72 + t] = kb4[i];
    }
    __syncthreads();

    // ---- G = K K^T (store lr*G fp32), A = Q K^T (store strict-lower bf16)
    bf16x8 afK[2], afQ[2], bfK[4][2];
    #pragma unroll
    for (int ks = 0; ks < 2; ++ks) {
        afK[ks] = *reinterpret_cast<const bf16x8*>(&K16[(w * 16 + m) * 72 + ks * 32 + quad * 8]);
        afQ[ks] = *reinterpret_cast<const bf16x8*>(&Q16[(w * 16 + m) * 72 + ks * 32 + quad * 8]);
        #pragma unroll
        for (int nt = 0; nt < 4; ++nt)
            bfK[nt][ks] = *reinterpret_cast<const bf16x8*>(&K16[(nt * 16 + m) * 72 + ks * 32 + quad * 8]);
    }
    f32x4 gacc[4] = {}, aacc[4] = {};
    #pragma unroll
    for (int ks = 0; ks < 2; ++ks)
        #pragma unroll
        for (int nt = 0; nt < 4; ++nt) {
            gacc[nt] = __builtin_amdgcn_mfma_f32_16x16x32_bf16(afK[ks], bfK[nt][ks], gacc[nt], 0, 0, 0);
            aacc[nt] = __builtin_amdgcn_mfma_f32_16x16x32_bf16(afQ[ks], bfK[nt][ks], aacc[nt], 0, 0, 0);
        }
    #pragma unroll
    for (int nt = 0; nt < 4; ++nt)
        #pragma unroll
        for (int r = 0; r < 4; ++r) {
            const int t = w * 16 + quad * 4 + r, j = nt * 16 + m;
            Gf[t * 65 + j] = TTT_LR * gacc[nt][r];
            Astl[t * 72 + j] = __float2bfloat16(j < t ? aacc[nt][r] : 0.f);
        }
    __syncthreads();

    // ---- serial forward-substitution: Minv = (I + lr*trilS(G))^-1 (fp32)
    if (tid < 64) {
        for (int t = 0; t < 64; ++t) {
            float acc = (t == tid) ? 1.f : 0.f;
            for (int i = 0; i < t; ++i)
                acc = fmaf(-Gf[t * 65 + i], Mf[i * 65 + tid], acc);
            Mf[t * 65 + tid] = acc;
        }
    }
    __syncthreads();

    // ---- lr*Minv -> bf16 (row + transposed)
    #pragma unroll
    for (int it = 0; it < 16; ++it) {
        const int e = tid + it * 256;           // 0..4095
        const int t = e >> 6, j = e & 63;
        const bf16 vb = __float2bfloat16(TTT_LR * Mf[t * 65 + j]);
        Minv16[t * 72 + j] = vb;
        MinvT16[j * 72 + t] = vb;
    }
    __syncthreads();

    // ---- B = (lr*Minv) * K  via mfma(Minv16 rows, Kt16 rows)
    bf16x8 afM[2], afA[2], afKt[2], bfKt[4][2], bfMt[4][2];
    #pragma unroll
    for (int ks = 0; ks < 2; ++ks) {
        afM[ks]  = *reinterpret_cast<const bf16x8*>(&Minv16[(w * 16 + m) * 72 + ks * 32 + quad * 8]);
        afA[ks]  = *reinterpret_cast<const bf16x8*>(&Astl[(w * 16 + m) * 72 + ks * 32 + quad * 8]);
        afKt[ks] = *reinterpret_cast<const bf16x8*>(&Kt16[(w * 16 + m) * 72 + ks * 32 + quad * 8]);
        #pragma unroll
        for (int nt = 0; nt < 4; ++nt) {
            bfKt[nt][ks] = *reinterpret_cast<const bf16x8*>(&Kt16[(nt * 16 + m) * 72 + ks * 32 + quad * 8]);
            bfMt[nt][ks] = *reinterpret_cast<const bf16x8*>(&MinvT16[(nt * 16 + m) * 72 + ks * 32 + quad * 8]);
        }
    }
    f32x4 bacc[4] = {};
    #pragma unroll
    for (int ks = 0; ks < 2; ++ks)
        #pragma unroll
        for (int nt = 0; nt < 4; ++nt)
            bacc[nt] = __builtin_amdgcn_mfma_f32_16x16x32_bf16(afM[ks], bfKt[nt][ks], bacc[nt], 0, 0, 0);
    #pragma unroll
    for (int nt = 0; nt < 4; ++nt)
        #pragma unroll
        for (int r = 0; r < 4; ++r) {
            const int t = w * 16 + quad * 4 + r, s = nt * 16 + m;
            BnegT[s * 72 + t] = __float2bfloat16(-bacc[nt][r]);
        }
    __syncthreads();

    // ---- Qt = Q - Astl*B (C-init = Q), AM = Astl*(lr*Minv),
    //      T' = -K^T B = mfma(Kt rows, BnegT rows),
    //      W  =  K^T (lr*Minv) = mfma(Kt rows, MinvT rows)
    f32x4 qtacc[4], amacc[4] = {}, tacc[4] = {}, wacc[4] = {};
    #pragma unroll
    for (int nt = 0; nt < 4; ++nt)
        #pragma unroll
        for (int r = 0; r < 4; ++r)
            qtacc[nt][r] = qp[(w * 16 + quad * 4 + r) * DSZ + nt * 16 + m];
    #pragma unroll
    for (int ks = 0; ks < 2; ++ks)
        #pragma unroll
        for (int nt = 0; nt < 4; ++nt) {
            const bf16x8 bfBn = *reinterpret_cast<const bf16x8*>(
                &BnegT[(nt * 16 + m) * 72 + ks * 32 + quad * 8]);
            qtacc[nt] = __builtin_amdgcn_mfma_f32_16x16x32_bf16(afA[ks], bfBn, qtacc[nt], 0, 0, 0);
            amacc[nt] = __builtin_amdgcn_mfma_f32_16x16x32_bf16(afA[ks], bfMt[nt][ks], amacc[nt], 0, 0, 0);
            tacc[nt]  = __builtin_amdgcn_mfma_f32_16x16x32_bf16(afKt[ks], bfBn, tacc[nt], 0, 0, 0);
            wacc[nt]  = __builtin_amdgcn_mfma_f32_16x16x32_bf16(afKt[ks], bfMt[nt][ks], wacc[nt], 0, 0, 0);
        }
    #pragma unroll
    for (int nt = 0; nt < 4; ++nt)
        #pragma unroll
        for (int r = 0; r < 4; ++r) {
            const int row = w * 16 + quad * 4 + r, col = nt * 16 + m;
            Qtb16[cb + row * 64 + col] = __float2bfloat16(qtacc[nt][r]);
            AMb16[cb + row * 64 + col] = __float2bfloat16(amacc[nt][r]);
            Tb16[cb + row * 64 + col]  = __float2bfloat16(tacc[nt][r]);
            Wb16[cb + row * 64 + col]  = __float2bfloat16(wacc[nt][r]);
        }
}

// ---------------------------------------------------------------------------
// Kernel 4: fused scan, ONE barrier per chunk. 256 blocks (64 d-stripes x
// 4 batches), 4 waves. Per chunk (8 MFMAs):
//   out  = x + AM V + Qt Z                         (single store)
//   zacc += T' Z + W V    (persistent fp32; Z_bf16 double-buffered in LDS)
// Z/V both read as B-frags from [d][.] LDS layouts; prefetch c+1 globals.
// Grid: 1-D 256 blocks with chunked XCD swizzle (b-major, dblk-fastest):
// 32 consecutive d-stripes of one b per XCD -> v16/x cache-line sharing is
// intra-XCD; T/W/AM/Qt chunk matrices fetched 2x (was 8x).
// ---------------------------------------------------------------------------
struct ChunkRegs {
    bf16x8 T0, T1, W0, W1, A0, A1, Q0, Q1;
    alignas(8) unsigned short va[4], vb[4];   // V rows (vj2, vj2+1) x 4 cols
    float xld[4];
};

__global__ __launch_bounds__(256) void scan2_kernel(
    const bf16* __restrict__ Tb16, const bf16* __restrict__ Wb16,
    const bf16* __restrict__ AMb16, const bf16* __restrict__ Qtb16,
    const bf16* __restrict__ v16, const float* __restrict__ x,
    float* __restrict__ out)
{
    __shared__ bf16 Zsh[2][16][72];
    __shared__ bf16 Vsh[2][16][72];
    // chunked XCD swizzle (256 % 8 == 0 -> bijective): tile = b*64 + dblk
    const int id = blockIdx.x;
    const int tile = (id & 7) * 32 + (id >> 3);
    const int b = tile >> 6, dblk = tile & 63;
    const int tid = threadIdx.x, lane = tid & 63, w = tid >> 6;
    const int m = lane & 15, quad = lane >> 4;
    const int d0 = dblk * 16;
    const int arow = w * 16 + m;          // A-frag row (all matmuls)
    const int trow = w * 16 + quad * 4;   // first C/D row for this thread

    // V staging: tid<128; row pair vj2, col group vd (4 cols)
    const bool vact = tid < 128;
    const int vj2 = (tid & 31) * 2;
    const int vd = (tid >> 5) * 4;        // 0,4,8,12 for tid<128

    f32x4 zacc = {0.f, 0.f, 0.f, 0.f};
    for (int i = tid; i < 16 * 72; i += 256)
        (&Zsh[0][0][0])[i] = __float2bfloat16(0.f);

    auto load_chunk = [&](int c, ChunkRegs& R) {
        const size_t cb = ((size_t)b * NC + c) * 4096;
        const size_t rowbase = (size_t)b * SS + (size_t)c * 64;
        R.T0 = *reinterpret_cast<const bf16x8*>(Tb16 + cb + arow * 64 + quad * 8);
        R.T1 = *reinterpret_cast<const bf16x8*>(Tb16 + cb + arow * 64 + 32 + quad * 8);
        R.W0 = *reinterpret_cast<const bf16x8*>(Wb16 + cb + arow * 64 + quad * 8);
        R.W1 = *reinterpret_cast<const bf16x8*>(Wb16 + cb + arow * 64 + 32 + quad * 8);
        R.A0 = *reinterpret_cast<const bf16x8*>(AMb16 + cb + arow * 64 + quad * 8);
        R.A1 = *reinterpret_cast<const bf16x8*>(AMb16 + cb + arow * 64 + 32 + quad * 8);
        R.Q0 = *reinterpret_cast<const bf16x8*>(Qtb16 + cb + arow * 64 + quad * 8);
        R.Q1 = *reinterpret_cast<const bf16x8*>(Qtb16 + cb + arow * 64 + 32 + quad * 8);
        if (vact) {
            *reinterpret_cast<uint2*>(R.va) = *reinterpret_cast<const uint2*>(
                v16 + (rowbase + vj2) * DD + d0 + vd);
            *reinterpret_cast<uint2*>(R.vb) = *reinterpret_cast<const uint2*>(
                v16 + (rowbase + vj2 + 1) * DD + d0 + vd);
        }
        const size_t gbase = (rowbase + trow) * DD + d0 + m;
        #pragma unroll
        for (int r = 0; r < 4; ++r) R.xld[r] = x[gbase + (size_t)r * DD];
    };

    auto stage_v = [&](const ChunkRegs& R, int buf) {
        if (vact) {
            #pragma unroll
            for (int i = 0; i < 4; ++i) {
                const unsigned int pack =
                    (unsigned int)R.va[i] | ((unsigned int)R.vb[i] << 16);
                *reinterpret_cast<unsigned int*>(&Vsh[buf][vd + i][vj2]) = pack;
            }
        }
    };

    auto compute = [&](const ChunkRegs& R, int c, int buf) {
        const size_t gbase = ((size_t)b * SS + (size_t)c * 64 + trow) * DD + d0 + m;
        const bf16x8 z0 = *reinterpret_cast<const bf16x8*>(&Zsh[buf][m][quad * 8]);
        const bf16x8 z1 = *reinterpret_cast<const bf16x8*>(&Zsh[buf][m][32 + quad * 8]);
        const bf16x8 v0 = *reinterpret_cast<const bf16x8*>(&Vsh[buf][m][quad * 8]);
        const bf16x8 v1 = *reinterpret_cast<const bf16x8*>(&Vsh[buf][m][32 + quad * 8]);

        // Z update (persistent fp32 accumulator, increment form)
        zacc = __builtin_amdgcn_mfma_f32_16x16x32_bf16(R.T0, z0, zacc, 0, 0, 0);
        zacc = __builtin_amdgcn_mfma_f32_16x16x32_bf16(R.T1, z1, zacc, 0, 0, 0);
        zacc = __builtin_amdgcn_mfma_f32_16x16x32_bf16(R.W0, v0, zacc, 0, 0, 0);
        zacc = __builtin_amdgcn_mfma_f32_16x16x32_bf16(R.W1, v1, zacc, 0, 0, 0);

        // y = Qt Z + AM V
        f32x4 y = {0.f, 0.f, 0.f, 0.f};
        y = __builtin_amdgcn_mfma_f32_16x16x32_bf16(R.Q0, z0, y, 0, 0, 0);
        y = __builtin_amdgcn_mfma_f32_16x16x32_bf16(R.Q1, z1, y, 0, 0, 0);
        y = __builtin_amdgcn_mfma_f32_16x16x32_bf16(R.A0, v0, y, 0, 0, 0);
        y = __builtin_amdgcn_mfma_f32_16x16x32_bf16(R.A1, v1, y, 0, 0, 0);

        // write new Z (bf16) into the other buffer
        alignas(8) bf16 zb[4];
        #pragma unroll
        for (int r = 0; r < 4; ++r) zb[r] = __float2bfloat16(zacc[r]);
        *reinterpret_cast<uint2*>(&Zsh[buf ^ 1][m][trow]) =
            *reinterpret_cast<uint2*>(zb);

        #pragma unroll
        for (int r = 0; r < 4; ++r)
            out[gbase + (size_t)r * DD] = R.xld[r] + y[r];
    };

    ChunkRegs R0, R1;
    load_chunk(0, R0);
    for (int c = 0; c < NC; c += 2) {
        // phase 0: chunk c (buffers 0), prefetch c+1
        stage_v(R0, 0);
        __syncthreads();                  // Vsh[0] + Zsh[0] ready
        load_chunk(c + 1, R1);
        compute(R0, c, 0);                // reads buf 0, writes Zsh[1]
        // phase 1: chunk c+1 (buffers 1), prefetch c+2
        stage_v(R1, 1);
        __syncthreads();                  // Vsh[1] + Zsh[1] ready
        if (c + 2 < NC) load_chunk(c + 2, R0);
        compute(R1, c + 1, 1);            // reads buf 1, writes Zsh[0]
    }
}

// ---------------------------------------------------------------------------
extern "C" void kernel_launch(void* const* d_in, const int* in_sizes, int n_in,
                              void* d_out, int out_size, void* d_ws, size_t ws_size,
                              hipStream_t stream)
{
    const float* x     = (const float*)d_in[0];
    const float* Wk    = (const float*)d_in[1];
    const float* bk    = (const float*)d_in[2];
    const float* Wv    = (const float*)d_in[3];
    const float* bv    = (const float*)d_in[4];
    const float* Wq    = (const float*)d_in[5];
    const float* bq    = (const float*)d_in[6];
    const float* gamma = (const float*)d_in[7];
    const float* beta  = (const float*)d_in[8];

    char* ws = (char*)d_ws;
    // layout (~38.25 MiB):
    //   [0,16 MiB): hb (bf16, pre->kqv) -- dead after kqv; reused by prep as:
    //     Tb16@0, Qtb16@1MiB, Wb16@2MiB, AMb16@3MiB (1 MiB each)
    //   [16 MiB, +2.25): Wcat (bf16 1152x1024)
    //   +2 MiB: kbuf (fp32)   +2 MiB: qbuf (fp32)
    //   +16 MiB: vbuf16 (bf16 8192x1024)
    const size_t WCAT_B = (size_t)NCAT * DD * 2;   // 2.25 MiB
    bf16*  hb    = (bf16*)ws;
    bf16*  Tb16  = (bf16*)(ws + 0 * MiB);
    bf16*  Qtb16 = (bf16*)(ws + 1 * MiB);
    bf16*  Wb16  = (bf16*)(ws + 2 * MiB);
    bf16*  AMb16 = (bf16*)(ws + 3 * MiB);
    bf16*  Wcat  = (bf16*)(ws + 16 * MiB);
    float* kbuf  = (float*)(ws + 16 * MiB + WCAT_B);
    float* qbuf  = (float*)(ws + 18 * MiB + WCAT_B);
    bf16*  v16   = (bf16*)(ws + 20 * MiB + WCAT_B);

    pre_kernel<<<NCVT + BB * SS, 256, 0, stream>>>(
        Wk, Wq, Wv, Wcat, x, gamma, beta, hb);
    kqv_kernel<<<dim3(1152), 256, 0, stream>>>(
        hb, Wcat, bk, bq, bv, kbuf, qbuf, v16);
    prep_kernel<<<dim3(NC, BB), 256, 0, stream>>>(
        kbuf, qbuf, Tb16, Wb16, AMb16, Qtb16);
    scan2_kernel<<<dim3(256), 256, 0, stream>>>(
        Tb16, Wb16, AMb16, Qtb16, v16, x, (float*)d_out);
}

// Round 13
// 205.116 us; speedup vs baseline: 1.0757x; 1.0150x over previous
//
#include <hip/hip_runtime.h>
#include <hip/hip_bf16.h>

#define TTT_LR 0.01f
#define LN_EPS 1e-5f

// Problem dims (fixed by reference)
#define BB 4
#define SS 2048
#define DD 1024
#define DSZ 64
#define CHUNK 64
#define NC (SS / CHUNK)   // 32
#define NCAT 1152         // 64 k + 64 q + 1024 v output cols
#define NCVT (NCAT * DD / 4 / 256)   // 1152 cvt blocks
#define MiB (1024ull * 1024ull)

typedef __hip_bfloat16 bf16;
typedef __bf16 bf16x8 __attribute__((ext_vector_type(8)));
typedef float f32x4 __attribute__((ext_vector_type(4)));

__device__ __forceinline__ void gload_lds16(const void* g, void* l) {
    __builtin_amdgcn_global_load_lds(
        (const __attribute__((address_space(1))) unsigned int*)g,
        (__attribute__((address_space(3))) unsigned int*)l, 16, 0, 0);
}

// lgkm-only barrier: LDS producer/consumer visibility WITHOUT the vmcnt(0)
// drain __syncthreads emits. Out-stores are never re-read and register loads
// are scoreboarded at use, so vmcnt need not drain at chunk boundaries.
// asm memory clobbers fence compiler code motion on both sides.
__device__ __forceinline__ void barrier_lgkm() {
    asm volatile("s_waitcnt lgkmcnt(0)" ::: "memory");
    __builtin_amdgcn_s_barrier();
    asm volatile("" ::: "memory");
}

// ---------------------------------------------------------------------------
// Kernel 1: merged pre-pass. Blocks [0,NCVT): Wk/Wq/Wv -> bf16 Wcat.
// Blocks [NCVT, NCVT+B*S): LayerNorm row -> h (bf16).
// ---------------------------------------------------------------------------
__global__ __launch_bounds__(256) void pre_kernel(
    const float* __restrict__ Wk, const float* __restrict__ Wq,
    const float* __restrict__ Wv, bf16* __restrict__ Wcat,
    const float* __restrict__ x, const float* __restrict__ gamma,
    const float* __restrict__ beta, bf16* __restrict__ hb)
{
    __shared__ float wsum[4], wsum2[4];
    const int tid = threadIdx.x;

    if (blockIdx.x < NCVT) {
        const int i = blockIdx.x * 256 + tid;           // float4 group index
        const int idx = i * 4;
        const int row = idx >> 10, col = idx & 1023;
        const float* src = (row < 64)  ? (Wk + (size_t)row * DD)
                         : (row < 128) ? (Wq + (size_t)(row - 64) * DD)
                                       : (Wv + (size_t)(row - 128) * DD);
        float4 v = *reinterpret_cast<const float4*>(src + col);
        bf16 h4[4] = {__float2bfloat16(v.x), __float2bfloat16(v.y),
                      __float2bfloat16(v.z), __float2bfloat16(v.w)};
        *reinterpret_cast<ushort4*>(Wcat + idx) = *reinterpret_cast<ushort4*>(h4);
        return;
    }

    const int row = blockIdx.x - NCVT;
    const int lane = tid & 63, wave = tid >> 6;

    float4 v0 = *reinterpret_cast<const float4*>(x + (size_t)row * DD + tid * 4);
    float s = v0.x + v0.y + v0.z + v0.w;
    float s2 = fmaf(v0.x, v0.x, fmaf(v0.y, v0.y, fmaf(v0.z, v0.z, v0.w * v0.w)));
    #pragma unroll
    for (int off = 32; off > 0; off >>= 1) {
        s  += __shfl_down(s, off, 64);
        s2 += __shfl_down(s2, off, 64);
    }
    if (lane == 0) { wsum[wave] = s; wsum2[wave] = s2; }
    __syncthreads();
    s  = wsum[0] + wsum[1] + wsum[2] + wsum[3];
    s2 = wsum2[0] + wsum2[1] + wsum2[2] + wsum2[3];
    const float mu = s * (1.0f / DD);
    const float rs = rsqrtf(s2 * (1.0f / DD) - mu * mu + LN_EPS);

    float4 g  = *reinterpret_cast<const float4*>(gamma + tid * 4);
    float4 be = *reinterpret_cast<const float4*>(beta + tid * 4);
    bf16 h4[4];
    h4[0] = __float2bfloat16((v0.x - mu) * rs * g.x + be.x);
    h4[1] = __float2bfloat16((v0.y - mu) * rs * g.y + be.y);
    h4[2] = __float2bfloat16((v0.z - mu) * rs * g.z + be.z);
    h4[3] = __float2bfloat16((v0.w - mu) * rs * g.w + be.w);
    *reinterpret_cast<ushort4*>(hb + (size_t)row * DD + tid * 4) =
        *reinterpret_cast<ushort4*>(h4);
}

// ---------------------------------------------------------------------------
// Kernel 2: fused kqv = h @ Wcat^T + bias. 64x128 tile, BK=64,
// global_load_lds(16B) staging, XOR-swizzled 16B blocks. k/q stored fp32;
// v stored bf16 (vbuf16) for the MFMA scan.
// R11 verified: this retile + XCD swizzle dropped kqv out of the top-5
// (was 47us at 2.25 blocks/CU). Grid 1152 = 4.5 blocks/CU (18 waves/CU).
// ---------------------------------------------------------------------------
__global__ __launch_bounds__(256) void kqv_kernel(
    const bf16* __restrict__ h, const bf16* __restrict__ Wcat,
    const float* __restrict__ bk, const float* __restrict__ bq,
    const float* __restrict__ bv,
    float* __restrict__ kbuf, float* __restrict__ qbuf, bf16* __restrict__ vbuf16)
{
    __shared__ bf16 Ash[64 * 64];
    __shared__ bf16 Bsh[128 * 64];
    const int tid = threadIdx.x, lane = tid & 63, wave = tid >> 6;
    const int m = lane & 15, quad = lane >> 4;
    const int wr = wave >> 1, wc = wave & 1;   // wave owns 32x64 of 64x128

    // chunked XCD swizzle: hw assigns block id -> XCD (id % 8); logical tile
    // t on XCD t/144, so t = (id%8)*144 + id/8.
    const int id = blockIdx.x;
    const int tile = (id & 7) * 144 + (id >> 3);
    const int mtile = tile / 9;          // 0..127 M-panel (64 rows)
    const int ntile = tile % 9;          // 0..8   N-panel (n-fastest in-XCD)
    const int m0 = mtile * 64;           // h rows
    const int n0 = ntile * 128;          // Wcat rows

    const int srow = wave * 8 + (lane >> 3);   // staging row (+ i*32)
    const int scb = lane & 7;                  // staging 16B-block in row

    f32x4 acc[2][4] = {};

    for (int k0 = 0; k0 < DD; k0 += 64) {
        __syncthreads();                       // prior frag reads done
        // A: 64 rows (2 calls), B: 128 rows (4 calls)
        #pragma unroll
        for (int i = 0; i < 2; ++i) {
            const int row = i * 32 + srow;
            const int g16 = scb ^ (row & 7);   // swizzled source block
            gload_lds16(h    + (size_t)(m0 + row) * DD + k0 + g16 * 8,
                        (char*)Ash + (size_t)(i * 32 + wave * 8) * 128);
        }
        #pragma unroll
        for (int i = 0; i < 4; ++i) {
            const int row = i * 32 + srow;
            const int g16 = scb ^ (row & 7);
            gload_lds16(Wcat + (size_t)(n0 + row) * DD + k0 + g16 * 8,
                        (char*)Bsh + (size_t)(i * 32 + wave * 8) * 128);
        }
        __syncthreads();                       // DMA drained (vmcnt0 @ barrier)
        #pragma unroll
        for (int ks = 0; ks < 2; ++ks) {
            bf16x8 af[2], bfr[4];
            #pragma unroll
            for (int mt = 0; mt < 2; ++mt) {
                const int row = wr * 32 + mt * 16 + m;
                const int kb = (ks * 4 + quad) ^ (row & 7);
                af[mt] = *reinterpret_cast<const bf16x8*>(&Ash[row * 64 + kb * 8]);
            }
            #pragma unroll
            for (int nt = 0; nt < 4; ++nt) {
                const int row = wc * 64 + nt * 16 + m;
                const int kb = (ks * 4 + quad) ^ (row & 7);
                bfr[nt] = *reinterpret_cast<const bf16x8*>(&Bsh[row * 64 + kb * 8]);
            }
            #pragma unroll
            for (int mt = 0; mt < 2; ++mt)
                #pragma unroll
                for (int nt = 0; nt < 4; ++nt)
                    acc[mt][nt] = __builtin_amdgcn_mfma_f32_16x16x32_bf16(
                        af[mt], bfr[nt], acc[mt][nt], 0, 0, 0);
        }
    }

    #pragma unroll
    for (int nt = 0; nt < 4; ++nt) {
        const int n = n0 + wc * 64 + nt * 16 + m;
        if (n < 64) {
            const float bias = bk[n];
            #pragma unroll
            for (int mt = 0; mt < 2; ++mt) {
                const int row = m0 + wr * 32 + mt * 16 + quad * 4;
                #pragma unroll
                for (int r = 0; r < 4; ++r)
                    kbuf[(size_t)(row + r) * DSZ + n] = acc[mt][nt][r] + bias;
            }
        } else if (n < 128) {
            const float bias = bq[n - 64];
            #pragma unroll
            for (int mt = 0; mt < 2; ++mt) {
                const int row = m0 + wr * 32 + mt * 16 + quad * 4;
                #pragma unroll
                for (int r = 0; r < 4; ++r)
                    qbuf[(size_t)(row + r) * DSZ + (n - 64)] = acc[mt][nt][r] + bias;
            }
        } else {
            const float bias = bv[n - 128];
            #pragma unroll
            for (int mt = 0; mt < 2; ++mt) {
                const int row = m0 + wr * 32 + mt * 16 + quad * 4;
                #pragma unroll
                for (int r = 0; r < 4; ++r)
                    vbuf16[(size_t)(row + r) * DD + (n - 128)] =
                        __float2bfloat16(acc[mt][nt][r] + bias);
            }
        }
    }
}

// ---------------------------------------------------------------------------
// Kernel 3: per-(b,chunk) prep — MFMA. Outputs 4 chunk matrices (bf16):
//   Qtb16 = Q - Astl*B          (A-rows = t)
//   AMb16 = Astl*(lr*Minv)      (A-rows = t)
//   Tb16  = -K^T B              (A-rows = s)   [Z-update transition]
//   Wb16  = K^T (lr*Minv)       (A-rows = s)   [Z-update drive]
// where B = (lr*Minv)*K, Minv = (I + lr*trilS(G))^-1 (serial solve, fp32),
// G = K K^T, A = Q K^T (strict-lower).
// ---------------------------------------------------------------------------
__global__ __launch_bounds__(256) void prep_kernel(
    const float* __restrict__ kbuf, const float* __restrict__ qbuf,
    bf16* __restrict__ Tb16, bf16* __restrict__ Wb16,
    bf16* __restrict__ AMb16, bf16* __restrict__ Qtb16)
{
    __shared__ bf16 K16[64 * 72];      // K  [t][s]
    __shared__ bf16 Kt16[64 * 72];     // K^T [s][t]
    __shared__ bf16 Q16[64 * 72];      // Q  [t][s]
    __shared__ bf16 Astl[64 * 72];     // strict-lower A, zeros elsewhere
    __shared__ bf16 Minv16[64 * 72];   // lr*Minv [t][j]
    __shared__ bf16 MinvT16[64 * 72];  // (lr*Minv)^T [j][t]
    __shared__ bf16 BnegT[64 * 72];    // -B^T [s][t]
    __shared__ float Gf[64 * 65];      // lr*G (fp32, solve input)
    __shared__ float Mf[64 * 65];      // Minv (fp32, solve output)

    const int c = blockIdx.x, b = blockIdx.y;
    const int tid = threadIdx.x, lane = tid & 63, w = tid >> 6;
    const int m = lane & 15, quad = lane >> 4;
    const float* kp = kbuf + ((size_t)b * SS + c * 64) * DSZ;
    const float* qp = qbuf + ((size_t)b * SS + c * 64) * DSZ;
    const size_t cb = ((size_t)b * NC + c) * 4096;

    // ---- stage K (row + transposed) and Q as bf16
    #pragma unroll
    for (int it = 0; it < 4; ++it) {
        const int f4 = tid + it * 256;          // float4 index 0..1023
        const int t = f4 >> 4;
        const int s = (f4 & 15) * 4;
        float4 kv = *reinterpret_cast<const float4*>(kp + t * DSZ + s);
        float4 qv = *reinterpret_cast<const float4*>(qp + t * DSZ + s);
        bf16 kb4[4] = {__float2bfloat16(kv.x), __float2bfloat16(kv.y),
                       __float2bfloat16(kv.z), __float2bfloat16(kv.w)};
        bf16 qb4[4] = {__float2bfloat16(qv.x), __float2bfloat16(qv.y),
                       __float2bfloat16(qv.z), __float2bfloat16(qv.w)};
        *reinterpret_cast<ushort4*>(&K16[t * 72 + s]) = *reinterpret_cast<ushort4*>(kb4);
        *reinterpret_cast<ushort4*>(&Q16[t * 72 + s]) = *reinterpret_cast<ushort4*>(qb4);
        #pragma unroll
        for (int i = 0; i < 4; ++i) Kt16[(s + i) * 72 + t] = kb4[i];
    }
    __syncthreads();

    // ---- G = K K^T (store lr*G fp32), A = Q K^T (store strict-lower bf16)
    bf16x8 afK[2], afQ[2], bfK[4][2];
    #pragma unroll
    for (int ks = 0; ks < 2; ++ks) {
        afK[ks] = *reinterpret_cast<const bf16x8*>(&K16[(w * 16 + m) * 72 + ks * 32 + quad * 8]);
        afQ[ks] = *reinterpret_cast<const bf16x8*>(&Q16[(w * 16 + m) * 72 + ks * 32 + quad * 8]);
        #pragma unroll
        for (int nt = 0; nt < 4; ++nt)
            bfK[nt][ks] = *reinterpret_cast<const bf16x8*>(&K16[(nt * 16 + m) * 72 + ks * 32 + quad * 8]);
    }
    f32x4 gacc[4] = {}, aacc[4] = {};
    #pragma unroll
    for (int ks = 0; ks < 2; ++ks)
        #pragma unroll
        for (int nt = 0; nt < 4; ++nt) {
            gacc[nt] = __builtin_amdgcn_mfma_f32_16x16x32_bf16(afK[ks], bfK[nt][ks], gacc[nt], 0, 0, 0);
            aacc[nt] = __builtin_amdgcn_mfma_f32_16x16x32_bf16(afQ[ks], bfK[nt][ks], aacc[nt], 0, 0, 0);
        }
    #pragma unroll
    for (int nt = 0; nt < 4; ++nt)
        #pragma unroll
        for (int r = 0; r < 4; ++r) {
            const int t = w * 16 + quad * 4 + r, j = nt * 16 + m;
            Gf[t * 65 + j] = TTT_LR * gacc[nt][r];
            Astl[t * 72 + j] = __float2bfloat16(j < t ? aacc[nt][r] : 0.f);
        }
    __syncthreads();

    // ---- serial forward-substitution: Minv = (I + lr*trilS(G))^-1 (fp32)
    if (tid < 64) {
        for (int t = 0; t < 64; ++t) {
            float acc = (t == tid) ? 1.f : 0.f;
            for (int i = 0; i < t; ++i)
                acc = fmaf(-Gf[t * 65 + i], Mf[i * 65 + tid], acc);
            Mf[t * 65 + tid] = acc;
        }
    }
    __syncthreads();

    // ---- lr*Minv -> bf16 (row + transposed)
    #pragma unroll
    for (int it = 0; it < 16; ++it) {
        const int e = tid + it * 256;           // 0..4095
        const int t = e >> 6, j = e & 63;
        const bf16 vb = __float2bfloat16(TTT_LR * Mf[t * 65 + j]);
        Minv16[t * 72 + j] = vb;
        MinvT16[j * 72 + t] = vb;
    }
    __syncthreads();

    // ---- B = (lr*Minv) * K  via mfma(Minv16 rows, Kt16 rows)
    bf16x8 afM[2], afA[2], afKt[2], bfKt[4][2], bfMt[4][2];
    #pragma unroll
    for (int ks = 0; ks < 2; ++ks) {
        afM[ks]  = *reinterpret_cast<const bf16x8*>(&Minv16[(w * 16 + m) * 72 + ks * 32 + quad * 8]);
        afA[ks]  = *reinterpret_cast<const bf16x8*>(&Astl[(w * 16 + m) * 72 + ks * 32 + quad * 8]);
        afKt[ks] = *reinterpret_cast<const bf16x8*>(&Kt16[(w * 16 + m) * 72 + ks * 32 + quad * 8]);
        #pragma unroll
        for (int nt = 0; nt < 4; ++nt) {
            bfKt[nt][ks] = *reinterpret_cast<const bf16x8*>(&Kt16[(nt * 16 + m) * 72 + ks * 32 + quad * 8]);
            bfMt[nt][ks] = *reinterpret_cast<const bf16x8*>(&MinvT16[(nt * 16 + m) * 72 + ks * 32 + quad * 8]);
        }
    }
    f32x4 bacc[4] = {};
    #pragma unroll
    for (int ks = 0; ks < 2; ++ks)
        #pragma unroll
        for (int nt = 0; nt < 4; ++nt)
            bacc[nt] = __builtin_amdgcn_mfma_f32_16x16x32_bf16(afM[ks], bfKt[nt][ks], bacc[nt], 0, 0, 0);
    #pragma unroll
    for (int nt = 0; nt < 4; ++nt)
        #pragma unroll
        for (int r = 0; r < 4; ++r) {
            const int t = w * 16 + quad * 4 + r, s = nt * 16 + m;
            BnegT[s * 72 + t] = __float2bfloat16(-bacc[nt][r]);
        }
    __syncthreads();

    // ---- Qt = Q - Astl*B (C-init = Q), AM = Astl*(lr*Minv),
    //      T' = -K^T B = mfma(Kt rows, BnegT rows),
    //      W  =  K^T (lr*Minv) = mfma(Kt rows, MinvT rows)
    f32x4 qtacc[4], amacc[4] = {}, tacc[4] = {}, wacc[4] = {};
    #pragma unroll
    for (int nt = 0; nt < 4; ++nt)
        #pragma unroll
        for (int r = 0; r < 4; ++r)
            qtacc[nt][r] = qp[(w * 16 + quad * 4 + r) * DSZ + nt * 16 + m];
    #pragma unroll
    for (int ks = 0; ks < 2; ++ks)
        #pragma unroll
        for (int nt = 0; nt < 4; ++nt) {
            const bf16x8 bfBn = *reinterpret_cast<const bf16x8*>(
                &BnegT[(nt * 16 + m) * 72 + ks * 32 + quad * 8]);
            qtacc[nt] = __builtin_amdgcn_mfma_f32_16x16x32_bf16(afA[ks], bfBn, qtacc[nt], 0, 0, 0);
            amacc[nt] = __builtin_amdgcn_mfma_f32_16x16x32_bf16(afA[ks], bfMt[nt][ks], amacc[nt], 0, 0, 0);
            tacc[nt]  = __builtin_amdgcn_mfma_f32_16x16x32_bf16(afKt[ks], bfBn, tacc[nt], 0, 0, 0);
            wacc[nt]  = __builtin_amdgcn_mfma_f32_16x16x32_bf16(afKt[ks], bfMt[nt][ks], wacc[nt], 0, 0, 0);
        }
    #pragma unroll
    for (int nt = 0; nt < 4; ++nt)
        #pragma unroll
        for (int r = 0; r < 4; ++r) {
            const int row = w * 16 + quad * 4 + r, col = nt * 16 + m;
            Qtb16[cb + row * 64 + col] = __float2bfloat16(qtacc[nt][r]);
            AMb16[cb + row * 64 + col] = __float2bfloat16(amacc[nt][r]);
            Tb16[cb + row * 64 + col]  = __float2bfloat16(tacc[nt][r]);
            Wb16[cb + row * 64 + col]  = __float2bfloat16(wacc[nt][r]);
        }
}

// ---------------------------------------------------------------------------
// Kernel 4: fused scan. 256 blocks (64 d-stripes x 4 b), 4 waves. Per chunk:
//   out  = x + AM V + Qt Z          zacc += T' Z + W V   (8 MFMAs)
// R11 counters: 46us, MfmaUtil 3%, HBM 17%, Occ 9.5% -> pure latency, and
// __syncthreads' vmcnt(0) drain serialized HBM store/load completion into
// every chunk. This version: (1) lgkm-only raw barrier (LDS visibility kept,
// vmcnt free-running); (2) V/x loads 2 phases deep (VRegs rotation); (3) Z
// LDS write hoisted before the y MFMAs. Same buffer invariants as before:
// between consecutive barriers, writes touch {Vsh[buf^1], Zsh[buf^1]} while
// reads touch {Vsh[buf], Zsh[buf]}.
// ---------------------------------------------------------------------------
struct MRegs { bf16x8 T0, T1, W0, W1, A0, A1, Q0, Q1; };
struct VRegs {
    alignas(8) unsigned short va[4], vb[4];   // V rows (vj2, vj2+1) x 4 cols
    float xld[4];
};

__global__ __launch_bounds__(256) void scan2_kernel(
    const bf16* __restrict__ Tb16, const bf16* __restrict__ Wb16,
    const bf16* __restrict__ AMb16, const bf16* __restrict__ Qtb16,
    const bf16* __restrict__ v16, const float* __restrict__ x,
    float* __restrict__ out)
{
    __shared__ bf16 Zsh[2][16][72];
    __shared__ bf16 Vsh[2][16][72];
    // chunked XCD swizzle (256 % 8 == 0 -> bijective): tile = b*64 + dblk
    const int id = blockIdx.x;
    const int tile = (id & 7) * 32 + (id >> 3);
    const int b = tile >> 6, dblk = tile & 63;
    const int tid = threadIdx.x, lane = tid & 63, w = tid >> 6;
    const int m = lane & 15, quad = lane >> 4;
    const int d0 = dblk * 16;
    const int arow = w * 16 + m;          // A-frag row (all matmuls)
    const int trow = w * 16 + quad * 4;   // first C/D row for this thread

    // V staging: tid<128; row pair vj2, col group vd (4 cols)
    const bool vact = tid < 128;
    const int vj2 = (tid & 31) * 2;
    const int vd = (tid >> 5) * 4;        // 0,4,8,12 for tid<128

    f32x4 zacc = {0.f, 0.f, 0.f, 0.f};
    for (int i = tid; i < 16 * 72; i += 256)
        (&Zsh[0][0][0])[i] = __float2bfloat16(0.f);

    auto load_m = [&](int c, MRegs& R) {
        const size_t cb = ((size_t)b * NC + c) * 4096;
        R.T0 = *reinterpret_cast<const bf16x8*>(Tb16 + cb + arow * 64 + quad * 8);
        R.T1 = *reinterpret_cast<const bf16x8*>(Tb16 + cb + arow * 64 + 32 + quad * 8);
        R.W0 = *reinterpret_cast<const bf16x8*>(Wb16 + cb + arow * 64 + quad * 8);
        R.W1 = *reinterpret_cast<const bf16x8*>(Wb16 + cb + arow * 64 + 32 + quad * 8);
        R.A0 = *reinterpret_cast<const bf16x8*>(AMb16 + cb + arow * 64 + quad * 8);
        R.A1 = *reinterpret_cast<const bf16x8*>(AMb16 + cb + arow * 64 + 32 + quad * 8);
        R.Q0 = *reinterpret_cast<const bf16x8*>(Qtb16 + cb + arow * 64 + quad * 8);
        R.Q1 = *reinterpret_cast<const bf16x8*>(Qtb16 + cb + arow * 64 + 32 + quad * 8);
    };

    auto load_v = [&](int c, VRegs& V) {
        const size_t rowbase = (size_t)b * SS + (size_t)c * 64;
        if (vact) {
            *reinterpret_cast<uint2*>(V.va) = *reinterpret_cast<const uint2*>(
                v16 + (rowbase + vj2) * DD + d0 + vd);
            *reinterpret_cast<uint2*>(V.vb) = *reinterpret_cast<const uint2*>(
                v16 + (rowbase + vj2 + 1) * DD + d0 + vd);
        }
        const size_t gbase = (rowbase + trow) * DD + d0 + m;
        #pragma unroll
        for (int r = 0; r < 4; ++r) V.xld[r] = x[gbase + (size_t)r * DD];
    };

    auto stage_v = [&](const VRegs& V, int buf) {
        if (vact) {
            #pragma unroll
            for (int i = 0; i < 4; ++i) {
                const unsigned int pack =
                    (unsigned int)V.va[i] | ((unsigned int)V.vb[i] << 16);
                *reinterpret_cast<unsigned int*>(&Vsh[buf][vd + i][vj2]) = pack;
            }
        }
    };

    auto compute = [&](const MRegs& R, const VRegs& V, int c, int buf) {
        const bf16x8 z0 = *reinterpret_cast<const bf16x8*>(&Zsh[buf][m][quad * 8]);
        const bf16x8 z1 = *reinterpret_cast<const bf16x8*>(&Zsh[buf][m][32 + quad * 8]);
        const bf16x8 v0 = *reinterpret_cast<const bf16x8*>(&Vsh[buf][m][quad * 8]);
        const bf16x8 v1 = *reinterpret_cast<const bf16x8*>(&Vsh[buf][m][32 + quad * 8]);

        // Z update first (critical path to next barrier)
        zacc = __builtin_amdgcn_mfma_f32_16x16x32_bf16(R.T0, z0, zacc, 0, 0, 0);
        zacc = __builtin_amdgcn_mfma_f32_16x16x32_bf16(R.T1, z1, zacc, 0, 0, 0);
        zacc = __builtin_amdgcn_mfma_f32_16x16x32_bf16(R.W0, v0, zacc, 0, 0, 0);
        zacc = __builtin_amdgcn_mfma_f32_16x16x32_bf16(R.W1, v1, zacc, 0, 0, 0);

        // write new Z (bf16) into the other buffer ASAP
        alignas(8) bf16 zb[4];
        #pragma unroll
        for (int r = 0; r < 4; ++r) zb[r] = __float2bfloat16(zacc[r]);
        *reinterpret_cast<uint2*>(&Zsh[buf ^ 1][m][trow]) =
            *reinterpret_cast<uint2*>(zb);

        // y = Qt Z + AM V (off the recurrence critical path)
        f32x4 y = {0.f, 0.f, 0.f, 0.f};
        y = __builtin_amdgcn_mfma_f32_16x16x32_bf16(R.Q0, z0, y, 0, 0, 0);
        y = __builtin_amdgcn_mfma_f32_16x16x32_bf16(R.Q1, z1, y, 0, 0, 0);
        y = __builtin_amdgcn_mfma_f32_16x16x32_bf16(R.A0, v0, y, 0, 0, 0);
        y = __builtin_amdgcn_mfma_f32_16x16x32_bf16(R.A1, v1, y, 0, 0, 0);

        const size_t gbase = ((size_t)b * SS + (size_t)c * 64 + trow) * DD + d0 + m;
        #pragma unroll
        for (int r = 0; r < 4; ++r)
            out[gbase + (size_t)r * DD] = V.xld[r] + y[r];
    };

    VRegs V0, V1;
    MRegs M0, M1;
    load_v(0, V0);
    load_v(1, V1);
    load_m(0, M0);
    for (int c = 0; c < NC; c += 2) {
        // phase A: chunk c (buffers 0)
        stage_v(V0, 0);
        barrier_lgkm();                   // Vsh[0] + Zsh[0] visible
        load_m(c + 1, M1);
        compute(M0, V0, c, 0);            // reads buf 0, writes Zsh[1]
        if (c + 2 < NC) load_v(c + 2, V0);   // 2-phase lead for V/x

        // phase B: chunk c+1 (buffers 1)
        stage_v(V1, 1);
        barrier_lgkm();                   // Vsh[1] + Zsh[1] visible
        if (c + 2 < NC) load_m(c + 2, M0);
        compute(M1, V1, c + 1, 1);        // reads buf 1, writes Zsh[0]
        if (c + 3 < NC) load_v(c + 3, V1);
    }
}

// ---------------------------------------------------------------------------
extern "C" void kernel_launch(void* const* d_in, const int* in_sizes, int n_in,
                              void* d_out, int out_size, void* d_ws, size_t ws_size,
                              hipStream_t stream)
{
    const float* x     = (const float*)d_in[0];
    const float* Wk    = (const float*)d_in[1];
    const float* bk    = (const float*)d_in[2];
    const float* Wv    = (const float*)d_in[3];
    const float* bv    = (const float*)d_in[4];
    const float* Wq    = (const float*)d_in[5];
    const float* bq    = (const float*)d_in[6];
    const float* gamma = (const float*)d_in[7];
    const float* beta  = (const float*)d_in[8];

    char* ws = (char*)d_ws;
    // layout (~38.25 MiB):
    //   [0,16 MiB): hb (bf16, pre->kqv) -- dead after kqv; reused by prep as:
    //     Tb16@0, Qtb16@1MiB, Wb16@2MiB, AMb16@3MiB (1 MiB each)
    //   [16 MiB, +2.25): Wcat (bf16 1152x1024)
    //   +2 MiB: kbuf (fp32)   +2 MiB: qbuf (fp32)
    //   +16 MiB: vbuf16 (bf16 8192x1024)
    const size_t WCAT_B = (size_t)NCAT * DD * 2;   // 2.25 MiB
    bf16*  hb    = (bf16*)ws;
    bf16*  Tb16  = (bf16*)(ws + 0 * MiB);
    bf16*  Qtb16 = (bf16*)(ws + 1 * MiB);
    bf16*  Wb16  = (bf16*)(ws + 2 * MiB);
    bf16*  AMb16 = (bf16*)(ws + 3 * MiB);
    bf16*  Wcat  = (bf16*)(ws + 16 * MiB);
    float* kbuf  = (float*)(ws + 16 * MiB + WCAT_B);
    float* qbuf  = (float*)(ws + 18 * MiB + WCAT_B);
    bf16*  v16   = (bf16*)(ws + 20 * MiB + WCAT_B);

    pre_kernel<<<NCVT + BB * SS, 256, 0, stream>>>(
        Wk, Wq, Wv, Wcat, x, gamma, beta, hb);
    kqv_kernel<<<dim3(1152), 256, 0, stream>>>(
        hb, Wcat, bk, bq, bv, kbuf, qbuf, v16);
    prep_kernel<<<dim3(NC, BB), 256, 0, stream>>>(
        kbuf, qbuf, Tb16, Wb16, AMb16, Qtb16);
    scan2_kernel<<<dim3(256), 256, 0, stream>>>(
        Tb16, Wb16, AMb16, Qtb16, v16, x, (float*)d_out);
}

// Round 16
// 196.275 us; speedup vs baseline: 1.1242x; 1.0450x over previous
//
#include <hip/hip_runtime.h>
#include <hip/hip_bf16.h>

#define TTT_LR 0.01f
#define LN_EPS 1e-5f

// Problem dims (fixed by reference)
#define BB 4
#define SS 2048
#define DD 1024
#define DSZ 64
#define CHUNK 64
#define NC (SS / CHUNK)   // 32
#define NCAT 1152         // 64 k + 64 q + 1024 v output cols
#define NCVT (NCAT * DD / 4 / 256)   // 1152 cvt blocks
#define MiB (1024ull * 1024ull)

typedef __hip_bfloat16 bf16;
typedef __bf16 bf16x8 __attribute__((ext_vector_type(8)));
typedef float f32x4 __attribute__((ext_vector_type(4)));

__device__ __forceinline__ void gload_lds16(const void* g, void* l) {
    __builtin_amdgcn_global_load_lds(
        (const __attribute__((address_space(1))) unsigned int*)g,
        (__attribute__((address_space(3))) unsigned int*)l, 16, 0, 0);
}

// lgkm-only barrier: LDS producer/consumer visibility WITHOUT the vmcnt(0)
// drain __syncthreads emits. Out-stores are never re-read and register loads
// are scoreboarded at use, so vmcnt need not drain at chunk boundaries.
// asm memory clobbers fence compiler code motion on both sides.
__device__ __forceinline__ void barrier_lgkm() {
    asm volatile("s_waitcnt lgkmcnt(0)" ::: "memory");
    __builtin_amdgcn_s_barrier();
    asm volatile("" ::: "memory");
}

// ---------------------------------------------------------------------------
// Kernel 1: merged pre-pass. Blocks [0,NCVT): Wk/Wq/Wv -> bf16 Wcat.
// Blocks [NCVT, NCVT+B*S): LayerNorm row -> h (bf16).
// ---------------------------------------------------------------------------
__global__ __launch_bounds__(256) void pre_kernel(
    const float* __restrict__ Wk, const float* __restrict__ Wq,
    const float* __restrict__ Wv, bf16* __restrict__ Wcat,
    const float* __restrict__ x, const float* __restrict__ gamma,
    const float* __restrict__ beta, bf16* __restrict__ hb)
{
    __shared__ float wsum[4], wsum2[4];
    const int tid = threadIdx.x;

    if (blockIdx.x < NCVT) {
        const int i = blockIdx.x * 256 + tid;           // float4 group index
        const int idx = i * 4;
        const int row = idx >> 10, col = idx & 1023;
        const float* src = (row < 64)  ? (Wk + (size_t)row * DD)
                         : (row < 128) ? (Wq + (size_t)(row - 64) * DD)
                                       : (Wv + (size_t)(row - 128) * DD);
        float4 v = *reinterpret_cast<const float4*>(src + col);
        bf16 h4[4] = {__float2bfloat16(v.x), __float2bfloat16(v.y),
                      __float2bfloat16(v.z), __float2bfloat16(v.w)};
        *reinterpret_cast<ushort4*>(Wcat + idx) = *reinterpret_cast<ushort4*>(h4);
        return;
    }

    const int row = blockIdx.x - NCVT;
    const int lane = tid & 63, wave = tid >> 6;

    float4 v0 = *reinterpret_cast<const float4*>(x + (size_t)row * DD + tid * 4);
    float s = v0.x + v0.y + v0.z + v0.w;
    float s2 = fmaf(v0.x, v0.x, fmaf(v0.y, v0.y, fmaf(v0.z, v0.z, v0.w * v0.w)));
    #pragma unroll
    for (int off = 32; off > 0; off >>= 1) {
        s  += __shfl_down(s, off, 64);
        s2 += __shfl_down(s2, off, 64);
    }
    if (lane == 0) { wsum[wave] = s; wsum2[wave] = s2; }
    __syncthreads();
    s  = wsum[0] + wsum[1] + wsum[2] + wsum[3];
    s2 = wsum2[0] + wsum2[1] + wsum2[2] + wsum2[3];
    const float mu = s * (1.0f / DD);
    const float rs = rsqrtf(s2 * (1.0f / DD) - mu * mu + LN_EPS);

    float4 g  = *reinterpret_cast<const float4*>(gamma + tid * 4);
    float4 be = *reinterpret_cast<const float4*>(beta + tid * 4);
    bf16 h4[4];
    h4[0] = __float2bfloat16((v0.x - mu) * rs * g.x + be.x);
    h4[1] = __float2bfloat16((v0.y - mu) * rs * g.y + be.y);
    h4[2] = __float2bfloat16((v0.z - mu) * rs * g.z + be.z);
    h4[3] = __float2bfloat16((v0.w - mu) * rs * g.w + be.w);
    *reinterpret_cast<ushort4*>(hb + (size_t)row * DD + tid * 4) =
        *reinterpret_cast<ushort4*>(h4);
}

// ---------------------------------------------------------------------------
// Kernel 2: fused kqv = h @ Wcat^T + bias. 64x128 tile, BK=64,
// global_load_lds(16B) staging, XOR-swizzled 16B blocks. k/q stored fp32;
// v stored bf16 (vbuf16) for the MFMA scan.
// R11 verified: this retile + XCD swizzle dropped kqv out of the top-5
// (was 47us at 2.25 blocks/CU). Grid 1152 = 4.5 blocks/CU (18 waves/CU).
// ---------------------------------------------------------------------------
__global__ __launch_bounds__(256) void kqv_kernel(
    const bf16* __restrict__ h, const bf16* __restrict__ Wcat,
    const float* __restrict__ bk, const float* __restrict__ bq,
    const float* __restrict__ bv,
    float* __restrict__ kbuf, float* __restrict__ qbuf, bf16* __restrict__ vbuf16)
{
    __shared__ bf16 Ash[64 * 64];
    __shared__ bf16 Bsh[128 * 64];
    const int tid = threadIdx.x, lane = tid & 63, wave = tid >> 6;
    const int m = lane & 15, quad = lane >> 4;
    const int wr = wave >> 1, wc = wave & 1;   // wave owns 32x64 of 64x128

    // chunked XCD swizzle: hw assigns block id -> XCD (id % 8); logical tile
    // t on XCD t/144, so t = (id%8)*144 + id/8.
    const int id = blockIdx.x;
    const int tile = (id & 7) * 144 + (id >> 3);
    const int mtile = tile / 9;          // 0..127 M-panel (64 rows)
    const int ntile = tile % 9;          // 0..8   N-panel (n-fastest in-XCD)
    const int m0 = mtile * 64;           // h rows
    const int n0 = ntile * 128;          // Wcat rows

    const int srow = wave * 8 + (lane >> 3);   // staging row (+ i*32)
    const int scb = lane & 7;                  // staging 16B-block in row

    f32x4 acc[2][4] = {};

    for (int k0 = 0; k0 < DD; k0 += 64) {
        __syncthreads();                       // prior frag reads done
        // A: 64 rows (2 calls), B: 128 rows (4 calls)
        #pragma unroll
        for (int i = 0; i < 2; ++i) {
            const int row = i * 32 + srow;
            const int g16 = scb ^ (row & 7);   // swizzled source block
            gload_lds16(h    + (size_t)(m0 + row) * DD + k0 + g16 * 8,
                        (char*)Ash + (size_t)(i * 32 + wave * 8) * 128);
        }
        #pragma unroll
        for (int i = 0; i < 4; ++i) {
            const int row = i * 32 + srow;
            const int g16 = scb ^ (row & 7);
            gload_lds16(Wcat + (size_t)(n0 + row) * DD + k0 + g16 * 8,
                        (char*)Bsh + (size_t)(i * 32 + wave * 8) * 128);
        }
        __syncthreads();                       // DMA drained (vmcnt0 @ barrier)
        #pragma unroll
        for (int ks = 0; ks < 2; ++ks) {
            bf16x8 af[2], bfr[4];
            #pragma unroll
            for (int mt = 0; mt < 2; ++mt) {
                const int row = wr * 32 + mt * 16 + m;
                const int kb = (ks * 4 + quad) ^ (row & 7);
                af[mt] = *reinterpret_cast<const bf16x8*>(&Ash[row * 64 + kb * 8]);
            }
            #pragma unroll
            for (int nt = 0; nt < 4; ++nt) {
                const int row = wc * 64 + nt * 16 + m;
                const int kb = (ks * 4 + quad) ^ (row & 7);
                bfr[nt] = *reinterpret_cast<const bf16x8*>(&Bsh[row * 64 + kb * 8]);
            }
            #pragma unroll
            for (int mt = 0; mt < 2; ++mt)
                #pragma unroll
                for (int nt = 0; nt < 4; ++nt)
                    acc[mt][nt] = __builtin_amdgcn_mfma_f32_16x16x32_bf16(
                        af[mt], bfr[nt], acc[mt][nt], 0, 0, 0);
        }
    }

    #pragma unroll
    for (int nt = 0; nt < 4; ++nt) {
        const int n = n0 + wc * 64 + nt * 16 + m;
        if (n < 64) {
            const float bias = bk[n];
            #pragma unroll
            for (int mt = 0; mt < 2; ++mt) {
                const int row = m0 + wr * 32 + mt * 16 + quad * 4;
                #pragma unroll
                for (int r = 0; r < 4; ++r)
                    kbuf[(size_t)(row + r) * DSZ + n] = acc[mt][nt][r] + bias;
            }
        } else if (n < 128) {
            const float bias = bq[n - 64];
            #pragma unroll
            for (int mt = 0; mt < 2; ++mt) {
                const int row = m0 + wr * 32 + mt * 16 + quad * 4;
                #pragma unroll
                for (int r = 0; r < 4; ++r)
                    qbuf[(size_t)(row + r) * DSZ + (n - 64)] = acc[mt][nt][r] + bias;
            }
        } else {
            const float bias = bv[n - 128];
            #pragma unroll
            for (int mt = 0; mt < 2; ++mt) {
                const int row = m0 + wr * 32 + mt * 16 + quad * 4;
                #pragma unroll
                for (int r = 0; r < 4; ++r)
                    vbuf16[(size_t)(row + r) * DD + (n - 128)] =
                        __float2bfloat16(acc[mt][nt][r] + bias);
            }
        }
    }
}

// ---------------------------------------------------------------------------
// Kernel 3: per-(b,chunk) prep — MFMA. Outputs 4 chunk matrices (bf16).
// R13 counters: 49.5us, MfmaUtil 0.3%, VALUBusy 2%, Occ 5% -> the serial
// forward-substitution (2080 dependent scalar LDS read+fma iters, dynamic
// bound, one wave) dominated. Rewrite: Minv stored TRANSPOSED per-column
// contiguous (MfT[col][i], stride 68, 16B-aligned) and zero-initialized;
// each row t then reads the FULL 64-elem column as 16 float4 loads --
// entries i>=t are still zero (written at future t), so the full dot equals
// the strict-lower recurrence. Fixed trip count -> unrolled, pipelined
// reads, 4 partial accumulators (no serial fma chain).
// ---------------------------------------------------------------------------
__global__ __launch_bounds__(256) void prep_kernel(
    const float* __restrict__ kbuf, const float* __restrict__ qbuf,
    bf16* __restrict__ Tb16, bf16* __restrict__ Wb16,
    bf16* __restrict__ AMb16, bf16* __restrict__ Qtb16)
{
    __shared__ bf16 K16[64 * 72];      // K  [t][s]
    __shared__ bf16 Kt16[64 * 72];     // K^T [s][t]
    __shared__ bf16 Q16[64 * 72];      // Q  [t][s]
    __shared__ bf16 Astl[64 * 72];     // strict-lower A, zeros elsewhere
    __shared__ bf16 Minv16[64 * 72];   // lr*Minv [t][j]
    __shared__ bf16 MinvT16[64 * 72];  // (lr*Minv)^T [j][t]
    __shared__ bf16 BnegT[64 * 72];    // -B^T [s][t]
    __shared__ __align__(16) float Gf[64 * 68];   // lr*G (fp32, full), stride 68
    __shared__ __align__(16) float MfT[64 * 68];  // Minv^T [col][row], stride 68

    const int c = blockIdx.x, b = blockIdx.y;
    const int tid = threadIdx.x, lane = tid & 63, w = tid >> 6;
    const int m = lane & 15, quad = lane >> 4;
    const float* kp = kbuf + ((size_t)b * SS + c * 64) * DSZ;
    const float* qp = qbuf + ((size_t)b * SS + c * 64) * DSZ;
    const size_t cb = ((size_t)b * NC + c) * 4096;

    // ---- stage K (row + transposed) and Q as bf16
    #pragma unroll
    for (int it = 0; it < 4; ++it) {
        const int f4 = tid + it * 256;          // float4 index 0..1023
        const int t = f4 >> 4;
        const int s = (f4 & 15) * 4;
        float4 kv = *reinterpret_cast<const float4*>(kp + t * DSZ + s);
        float4 qv = *reinterpret_cast<const float4*>(qp + t * DSZ + s);
        bf16 kb4[4] = {__float2bfloat16(kv.x), __float2bfloat16(kv.y),
                       __float2bfloat16(kv.z), __float2bfloat16(kv.w)};
        bf16 qb4[4] = {__float2bfloat16(qv.x), __float2bfloat16(qv.y),
                       __float2bfloat16(qv.z), __float2bfloat16(qv.w)};
        *reinterpret_cast<ushort4*>(&K16[t * 72 + s]) = *reinterpret_cast<ushort4*>(kb4);
        *reinterpret_cast<ushort4*>(&Q16[t * 72 + s]) = *reinterpret_cast<ushort4*>(qb4);
        #pragma unroll
        for (int i = 0; i < 4; ++i) Kt16[(s + i) * 72 + t] = kb4[i];
    }
    // zero-init MfT (needed for the fixed-trip solve's padding trick)
    #pragma unroll
    for (int i = tid; i < 64 * 68; i += 256) MfT[i] = 0.f;
    __syncthreads();

    // ---- G = K K^T (store lr*G fp32), A = Q K^T (store strict-lower bf16)
    bf16x8 afK[2], afQ[2], bfK[4][2];
    #pragma unroll
    for (int ks = 0; ks < 2; ++ks) {
        afK[ks] = *reinterpret_cast<const bf16x8*>(&K16[(w * 16 + m) * 72 + ks * 32 + quad * 8]);
        afQ[ks] = *reinterpret_cast<const bf16x8*>(&Q16[(w * 16 + m) * 72 + ks * 32 + quad * 8]);
        #pragma unroll
        for (int nt = 0; nt < 4; ++nt)
            bfK[nt][ks] = *reinterpret_cast<const bf16x8*>(&K16[(nt * 16 + m) * 72 + ks * 32 + quad * 8]);
    }
    f32x4 gacc[4] = {}, aacc[4] = {};
    #pragma unroll
    for (int ks = 0; ks < 2; ++ks)
        #pragma unroll
        for (int nt = 0; nt < 4; ++nt) {
            gacc[nt] = __builtin_amdgcn_mfma_f32_16x16x32_bf16(afK[ks], bfK[nt][ks], gacc[nt], 0, 0, 0);
            aacc[nt] = __builtin_amdgcn_mfma_f32_16x16x32_bf16(afQ[ks], bfK[nt][ks], aacc[nt], 0, 0, 0);
        }
    #pragma unroll
    for (int nt = 0; nt < 4; ++nt)
        #pragma unroll
        for (int r = 0; r < 4; ++r) {
            const int t = w * 16 + quad * 4 + r, j = nt * 16 + m;
            Gf[t * 68 + j] = TTT_LR * gacc[nt][r];
            Astl[t * 72 + j] = __float2bfloat16(j < t ? aacc[nt][r] : 0.f);
        }
    __syncthreads();

    // ---- forward-substitution, fixed-trip vectorized:
    // MfT[col][i] holds Minv[i][col]; rows >= t are zero when row t is
    // computed, so the full 64-wide dot equals the strict-lower sum.
    if (tid < 64) {
        for (int t = 0; t < 64; ++t) {
            float a0 = 0.f, a1 = 0.f, a2 = 0.f, a3 = 0.f;
            #pragma unroll
            for (int i4 = 0; i4 < 16; ++i4) {
                const float4 g4 = *reinterpret_cast<const float4*>(&Gf[t * 68 + i4 * 4]);
                const float4 m4 = *reinterpret_cast<const float4*>(&MfT[tid * 68 + i4 * 4]);
                a0 = fmaf(g4.x, m4.x, a0);
                a1 = fmaf(g4.y, m4.y, a1);
                a2 = fmaf(g4.z, m4.z, a2);
                a3 = fmaf(g4.w, m4.w, a3);
            }
            MfT[tid * 68 + t] = ((t == tid) ? 1.f : 0.f) - ((a0 + a1) + (a2 + a3));
        }
    }
    __syncthreads();

    // ---- lr*Minv -> bf16 (row + transposed); Minv[t][j] = MfT[j][t]
    #pragma unroll
    for (int it = 0; it < 16; ++it) {
        const int e = tid + it * 256;           // 0..4095
        const int t = e >> 6, j = e & 63;
        const bf16 vb = __float2bfloat16(TTT_LR * MfT[j * 68 + t]);
        Minv16[t * 72 + j] = vb;
        MinvT16[j * 72 + t] = vb;
    }
    __syncthreads();

    // ---- B = (lr*Minv) * K  via mfma(Minv16 rows, Kt16 rows)
    bf16x8 afM[2], afA[2], afKt[2], bfKt[4][2], bfMt[4][2];
    #pragma unroll
    for (int ks = 0; ks < 2; ++ks) {
        afM[ks]  = *reinterpret_cast<const bf16x8*>(&Minv16[(w * 16 + m) * 72 + ks * 32 + quad * 8]);
        afA[ks]  = *reinterpret_cast<const bf16x8*>(&Astl[(w * 16 + m) * 72 + ks * 32 + quad * 8]);
        afKt[ks] = *reinterpret_cast<const bf16x8*>(&Kt16[(w * 16 + m) * 72 + ks * 32 + quad * 8]);
        #pragma unroll
        for (int nt = 0; nt < 4; ++nt) {
            bfKt[nt][ks] = *reinterpret_cast<const bf16x8*>(&Kt16[(nt * 16 + m) * 72 + ks * 32 + quad * 8]);
            bfMt[nt][ks] = *reinterpret_cast<const bf16x8*>(&MinvT16[(nt * 16 + m) * 72 + ks * 32 + quad * 8]);
        }
    }
    f32x4 bacc[4] = {};
    #pragma unroll
    for (int ks = 0; ks < 2; ++ks)
        #pragma unroll
        for (int nt = 0; nt < 4; ++nt)
            bacc[nt] = __builtin_amdgcn_mfma_f32_16x16x32_bf16(afM[ks], bfKt[nt][ks], bacc[nt], 0, 0, 0);
    #pragma unroll
    for (int nt = 0; nt < 4; ++nt)
        #pragma unroll
        for (int r = 0; r < 4; ++r) {
            const int t = w * 16 + quad * 4 + r, s = nt * 16 + m;
            BnegT[s * 72 + t] = __float2bfloat16(-bacc[nt][r]);
        }
    __syncthreads();

    // ---- Qt = Q - Astl*B (C-init = Q), AM = Astl*(lr*Minv),
    //      T' = -K^T B = mfma(Kt rows, BnegT rows),
    //      W  =  K^T (lr*Minv) = mfma(Kt rows, MinvT rows)
    f32x4 qtacc[4], amacc[4] = {}, tacc[4] = {}, wacc[4] = {};
    #pragma unroll
    for (int nt = 0; nt < 4; ++nt)
        #pragma unroll
        for (int r = 0; r < 4; ++r)
            qtacc[nt][r] = qp[(w * 16 + quad * 4 + r) * DSZ + nt * 16 + m];
    #pragma unroll
    for (int ks = 0; ks < 2; ++ks)
        #pragma unroll
        for (int nt = 0; nt < 4; ++nt) {
            const bf16x8 bfBn = *reinterpret_cast<const bf16x8*>(
                &BnegT[(nt * 16 + m) * 72 + ks * 32 + quad * 8]);
            qtacc[nt] = __builtin_amdgcn_mfma_f32_16x16x32_bf16(afA[ks], bfBn, qtacc[nt], 0, 0, 0);
            amacc[nt] = __builtin_amdgcn_mfma_f32_16x16x32_bf16(afA[ks], bfMt[nt][ks], amacc[nt], 0, 0, 0);
            tacc[nt]  = __builtin_amdgcn_mfma_f32_16x16x32_bf16(afKt[ks], bfBn, tacc[nt], 0, 0, 0);
            wacc[nt]  = __builtin_amdgcn_mfma_f32_16x16x32_bf16(afKt[ks], bfMt[nt][ks], wacc[nt], 0, 0, 0);
        }
    #pragma unroll
    for (int nt = 0; nt < 4; ++nt)
        #pragma unroll
        for (int r = 0; r < 4; ++r) {
            const int row = w * 16 + quad * 4 + r, col = nt * 16 + m;
            Qtb16[cb + row * 64 + col] = __float2bfloat16(qtacc[nt][r]);
            AMb16[cb + row * 64 + col] = __float2bfloat16(amacc[nt][r]);
            Tb16[cb + row * 64 + col]  = __float2bfloat16(tacc[nt][r]);
            Wb16[cb + row * 64 + col]  = __float2bfloat16(wacc[nt][r]);
        }
}

// ---------------------------------------------------------------------------
// Kernel 4: fused scan. 256 blocks (64 d-stripes x 4 b), 4 waves. Per chunk:
//   out  = x + AM V + Qt Z          zacc += T' Z + W V   (8 MFMAs)
// R13 verified: lgkm-only barrier + 2-deep V/x prefetch + hoisted Z-write
// moved scan2 below prep (was 46us).
// ---------------------------------------------------------------------------
struct MRegs { bf16x8 T0, T1, W0, W1, A0, A1, Q0, Q1; };
struct VRegs {
    alignas(8) unsigned short va[4], vb[4];   // V rows (vj2, vj2+1) x 4 cols
    float xld[4];
};

__global__ __launch_bounds__(256) void scan2_kernel(
    const bf16* __restrict__ Tb16, const bf16* __restrict__ Wb16,
    const bf16* __restrict__ AMb16, const bf16* __restrict__ Qtb16,
    const bf16* __restrict__ v16, const float* __restrict__ x,
    float* __restrict__ out)
{
    __shared__ bf16 Zsh[2][16][72];
    __shared__ bf16 Vsh[2][16][72];
    // chunked XCD swizzle (256 % 8 == 0 -> bijective): tile = b*64 + dblk
    const int id = blockIdx.x;
    const int tile = (id & 7) * 32 + (id >> 3);
    const int b = tile >> 6, dblk = tile & 63;
    const int tid = threadIdx.x, lane = tid & 63, w = tid >> 6;
    const int m = lane & 15, quad = lane >> 4;
    const int d0 = dblk * 16;
    const int arow = w * 16 + m;          // A-frag row (all matmuls)
    const int trow = w * 16 + quad * 4;   // first C/D row for this thread

    // V staging: tid<128; row pair vj2, col group vd (4 cols)
    const bool vact = tid < 128;
    const int vj2 = (tid & 31) * 2;
    const int vd = (tid >> 5) * 4;        // 0,4,8,12 for tid<128

    f32x4 zacc = {0.f, 0.f, 0.f, 0.f};
    for (int i = tid; i < 16 * 72; i += 256)
        (&Zsh[0][0][0])[i] = __float2bfloat16(0.f);

    auto load_m = [&](int c, MRegs& R) {
        const size_t cb = ((size_t)b * NC + c) * 4096;
        R.T0 = *reinterpret_cast<const bf16x8*>(Tb16 + cb + arow * 64 + quad * 8);
        R.T1 = *reinterpret_cast<const bf16x8*>(Tb16 + cb + arow * 64 + 32 + quad * 8);
        R.W0 = *reinterpret_cast<const bf16x8*>(Wb16 + cb + arow * 64 + quad * 8);
        R.W1 = *reinterpret_cast<const bf16x8*>(Wb16 + cb + arow * 64 + 32 + quad * 8);
        R.A0 = *reinterpret_cast<const bf16x8*>(AMb16 + cb + arow * 64 + quad * 8);
        R.A1 = *reinterpret_cast<const bf16x8*>(AMb16 + cb + arow * 64 + 32 + quad * 8);
        R.Q0 = *reinterpret_cast<const bf16x8*>(Qtb16 + cb + arow * 64 + quad * 8);
        R.Q1 = *reinterpret_cast<const bf16x8*>(Qtb16 + cb + arow * 64 + 32 + quad * 8);
    };

    auto load_v = [&](int c, VRegs& V) {
        const size_t rowbase = (size_t)b * SS + (size_t)c * 64;
        if (vact) {
            *reinterpret_cast<uint2*>(V.va) = *reinterpret_cast<const uint2*>(
                v16 + (rowbase + vj2) * DD + d0 + vd);
            *reinterpret_cast<uint2*>(V.vb) = *reinterpret_cast<const uint2*>(
                v16 + (rowbase + vj2 + 1) * DD + d0 + vd);
        }
        const size_t gbase = (rowbase + trow) * DD + d0 + m;
        #pragma unroll
        for (int r = 0; r < 4; ++r) V.xld[r] = x[gbase + (size_t)r * DD];
    };

    auto stage_v = [&](const VRegs& V, int buf) {
        if (vact) {
            #pragma unroll
            for (int i = 0; i < 4; ++i) {
                const unsigned int pack =
                    (unsigned int)V.va[i] | ((unsigned int)V.vb[i] << 16);
                *reinterpret_cast<unsigned int*>(&Vsh[buf][vd + i][vj2]) = pack;
            }
        }
    };

    auto compute = [&](const MRegs& R, const VRegs& V, int c, int buf) {
        const bf16x8 z0 = *reinterpret_cast<const bf16x8*>(&Zsh[buf][m][quad * 8]);
        const bf16x8 z1 = *reinterpret_cast<const bf16x8*>(&Zsh[buf][m][32 + quad * 8]);
        const bf16x8 v0 = *reinterpret_cast<const bf16x8*>(&Vsh[buf][m][quad * 8]);
        const bf16x8 v1 = *reinterpret_cast<const bf16x8*>(&Vsh[buf][m][32 + quad * 8]);

        // Z update first (critical path to next barrier)
        zacc = __builtin_amdgcn_mfma_f32_16x16x32_bf16(R.T0, z0, zacc, 0, 0, 0);
        zacc = __builtin_amdgcn_mfma_f32_16x16x32_bf16(R.T1, z1, zacc, 0, 0, 0);
        zacc = __builtin_amdgcn_mfma_f32_16x16x32_bf16(R.W0, v0, zacc, 0, 0, 0);
        zacc = __builtin_amdgcn_mfma_f32_16x16x32_bf16(R.W1, v1, zacc, 0, 0, 0);

        // write new Z (bf16) into the other buffer ASAP
        alignas(8) bf16 zb[4];
        #pragma unroll
        for (int r = 0; r < 4; ++r) zb[r] = __float2bfloat16(zacc[r]);
        *reinterpret_cast<uint2*>(&Zsh[buf ^ 1][m][trow]) =
            *reinterpret_cast<uint2*>(zb);

        // y = Qt Z + AM V (off the recurrence critical path)
        f32x4 y = {0.f, 0.f, 0.f, 0.f};
        y = __builtin_amdgcn_mfma_f32_16x16x32_bf16(R.Q0, z0, y, 0, 0, 0);
        y = __builtin_amdgcn_mfma_f32_16x16x32_bf16(R.Q1, z1, y, 0, 0, 0);
        y = __builtin_amdgcn_mfma_f32_16x16x32_bf16(R.A0, v0, y, 0, 0, 0);
        y = __builtin_amdgcn_mfma_f32_16x16x32_bf16(R.A1, v1, y, 0, 0, 0);

        const size_t gbase = ((size_t)b * SS + (size_t)c * 64 + trow) * DD + d0 + m;
        #pragma unroll
        for (int r = 0; r < 4; ++r)
            out[gbase + (size_t)r * DD] = V.xld[r] + y[r];
    };

    VRegs V0, V1;
    MRegs M0, M1;
    load_v(0, V0);
    load_v(1, V1);
    load_m(0, M0);
    for (int c = 0; c < NC; c += 2) {
        // phase A: chunk c (buffers 0)
        stage_v(V0, 0);
        barrier_lgkm();                   // Vsh[0] + Zsh[0] visible
        load_m(c + 1, M1);
        compute(M0, V0, c, 0);            // reads buf 0, writes Zsh[1]
        if (c + 2 < NC) load_v(c + 2, V0);   // 2-phase lead for V/x

        // phase B: chunk c+1 (buffers 1)
        stage_v(V1, 1);
        barrier_lgkm();                   // Vsh[1] + Zsh[1] visible
        if (c + 2 < NC) load_m(c + 2, M0);
        compute(M1, V1, c + 1, 1);        // reads buf 1, writes Zsh[0]
        if (c + 3 < NC) load_v(c + 3, V1);
    }
}

// ---------------------------------------------------------------------------
extern "C" void kernel_launch(void* const* d_in, const int* in_sizes, int n_in,
                              void* d_out, int out_size, void* d_ws, size_t ws_size,
                              hipStream_t stream)
{
    const float* x     = (const float*)d_in[0];
    const float* Wk    = (const float*)d_in[1];
    const float* bk    = (const float*)d_in[2];
    const float* Wv    = (const float*)d_in[3];
    const float* bv    = (const float*)d_in[4];
    const float* Wq    = (const float*)d_in[5];
    const float* bq    = (const float*)d_in[6];
    const float* gamma = (const float*)d_in[7];
    const float* beta  = (const float*)d_in[8];

    char* ws = (char*)d_ws;
    // layout (~38.25 MiB):
    //   [0,16 MiB): hb (bf16, pre->kqv) -- dead after kqv; reused by prep as:
    //     Tb16@0, Qtb16@1MiB, Wb16@2MiB, AMb16@3MiB (1 MiB each)
    //   [16 MiB, +2.25): Wcat (bf16 1152x1024)
    //   +2 MiB: kbuf (fp32)   +2 MiB: qbuf (fp32)
    //   +16 MiB: vbuf16 (bf16 8192x1024)
    const size_t WCAT_B = (size_t)NCAT * DD * 2;   // 2.25 MiB
    bf16*  hb    = (bf16*)ws;
    bf16*  Tb16  = (bf16*)(ws + 0 * MiB);
    bf16*  Qtb16 = (bf16*)(ws + 1 * MiB);
    bf16*  Wb16  = (bf16*)(ws + 2 * MiB);
    bf16*  AMb16 = (bf16*)(ws + 3 * MiB);
    bf16*  Wcat  = (bf16*)(ws + 16 * MiB);
    float* kbuf  = (float*)(ws + 16 * MiB + WCAT_B);
    float* qbuf  = (float*)(ws + 18 * MiB + WCAT_B);
    bf16*  v16   = (bf16*)(ws + 20 * MiB + WCAT_B);

    pre_kernel<<<NCVT + BB * SS, 256, 0, stream>>>(
        Wk, Wq, Wv, Wcat, x, gamma, beta, hb);
    kqv_kernel<<<dim3(1152), 256, 0, stream>>>(
        hb, Wcat, bk, bq, bv, kbuf, qbuf, v16);
    prep_kernel<<<dim3(NC, BB), 256, 0, stream>>>(
        kbuf, qbuf, Tb16, Wb16, AMb16, Qtb16);
    scan2_kernel<<<dim3(256), 256, 0, stream>>>(
        Tb16, Wb16, AMb16, Qtb16, v16, x, (float*)d_out);
}